// Round 7
// baseline (293.154 us; speedup 1.0000x reference)
//
#include <hip/hip_runtime.h>

#define NBQ 12544
#define DM  256
#define MM  2048

typedef __attribute__((ext_vector_type(8)))  __bf16 bf16x8;
typedef __attribute__((ext_vector_type(4)))  float  floatx4;

__device__ __forceinline__ ushort f2bf(float x) {
    unsigned u = __float_as_uint(x);
    u += 0x7fffu + ((u >> 16) & 1u);   // RNE
    return (ushort)(u >> 16);
}
__device__ __forceinline__ float bf2f(ushort h) {
    return __uint_as_float(((unsigned)h) << 16);
}
__device__ __forceinline__ ushort4 cvt4(float4 f) {   // HW bf16 cvt (RNE, = f2bf)
    union { __bf16 h[4]; ushort4 u; } r;
    r.h[0] = (__bf16)f.x; r.h[1] = (__bf16)f.y;
    r.h[2] = (__bf16)f.z; r.h[3] = (__bf16)f.w;
    return r.u;
}

// async global->LDS, 16B per lane; dest = wave-uniform base + lane*16
__device__ __forceinline__ void glds16(const ushort* g, ushort* l) {
    __builtin_amdgcn_global_load_lds(
        (const __attribute__((address_space(1))) unsigned int*)g,
        (__attribute__((address_space(3))) unsigned int*)l, 16, 0, 0);
}

// ---------- projections, weight-pairs folded; 2-phase reg prefetch ----------
__global__ __launch_bounds__(256) void gemm_proj_all(
    const float* __restrict__ x,      const float* __restrict__ ch_mem,
    const float* __restrict__ ch_wq,  const float* __restrict__ ch_wk,
    const float* __restrict__ ch_wv,  const float* __restrict__ sp_mem,
    const float* __restrict__ sp_wq,  const float* __restrict__ sp_wk,
    const float* __restrict__ sp_wv,
    ushort* __restrict__ Qb,  ushort* __restrict__ QFb,
    ushort* __restrict__ Kb,  ushort* __restrict__ KFb,
    ushort* __restrict__ Vtb, ushort* __restrict__ VFtb)
{
    __shared__ ushort As[64][72];
    __shared__ ushort W1s[64][72];
    __shared__ ushort W2s[64][72];

    int bid = blockIdx.x;
    const float* A; const float* W1; const float* W2;
    ushort* C1; ushort* C2; int nrows, trans2;
    if (bid < 784) {
        A = x; W1 = ch_wq; W2 = sp_wq; C1 = Qb; C2 = QFb; nrows = NBQ; trans2 = 0;
    } else if (bid < 912) {
        A = ch_mem; W1 = ch_wk; W2 = ch_wv; C1 = Kb; C2 = Vtb;
        nrows = MM; trans2 = 1; bid -= 784;
    } else {
        A = sp_mem; W1 = sp_wk; W2 = sp_wv; C1 = KFb; C2 = VFtb;
        nrows = MM; trans2 = 1; bid -= 912;
    }
    const int r0 = (bid >> 2) * 64;
    const int c0 = (bid & 3) * 64;

    const int tid  = threadIdx.x;
    const int wv   = tid >> 6;
    const int lane = tid & 63;
    const int quad = lane >> 4;
    const int l16  = lane & 15;
    const int rw = (wv & 1) * 32;
    const int cw = (wv >> 1) * 32;

    floatx4 acc1[2][2], acc2[2][2];
    #pragma unroll
    for (int i = 0; i < 2; ++i)
        #pragma unroll
        for (int j = 0; j < 2; ++j) {
            acc1[i][j] = (floatx4){0.f, 0.f, 0.f, 0.f};
            acc2[i][j] = (floatx4){0.f, 0.f, 0.f, 0.f};
        }

    float4 a4[4], w14[4], w24[4];
    #pragma unroll
    for (int it = 0; it < 4; ++it) {
        int idx = tid + it * 256;
        int r = idx >> 4, c4 = (idx & 15) * 4;
        a4[it]  = *(const float4*)(A  + (size_t)(r0 + r) * 256 + c4);
        w14[it] = *(const float4*)(W1 + (size_t)(c0 + r) * 256 + c4);
        w24[it] = *(const float4*)(W2 + (size_t)(c0 + r) * 256 + c4);
    }

    for (int d0 = 0; d0 < 256; d0 += 64) {
        __syncthreads();
        #pragma unroll
        for (int it = 0; it < 4; ++it) {
            int idx = tid + it * 256;
            int r = idx >> 4, c4 = (idx & 15) * 4;
            *(ushort4*)&As[r][c4]  = cvt4(a4[it]);
            *(ushort4*)&W1s[r][c4] = cvt4(w14[it]);
            *(ushort4*)&W2s[r][c4] = cvt4(w24[it]);
        }
        if (d0 + 64 < 256) {
            #pragma unroll
            for (int it = 0; it < 4; ++it) {
                int idx = tid + it * 256;
                int r = idx >> 4, c4 = (idx & 15) * 4;
                a4[it]  = *(const float4*)(A  + (size_t)(r0 + r) * 256 + d0 + 64 + c4);
                w14[it] = *(const float4*)(W1 + (size_t)(c0 + r) * 256 + d0 + 64 + c4);
                w24[it] = *(const float4*)(W2 + (size_t)(c0 + r) * 256 + d0 + 64 + c4);
            }
        }
        __syncthreads();
        #pragma unroll
        for (int kk = 0; kk < 64; kk += 32) {
            bf16x8 aA0 = *(const bf16x8*)&As[rw + l16][kk + quad * 8];
            bf16x8 aA1 = *(const bf16x8*)&As[rw + 16 + l16][kk + quad * 8];
            bf16x8 b10 = *(const bf16x8*)&W1s[cw + l16][kk + quad * 8];
            bf16x8 b11 = *(const bf16x8*)&W1s[cw + 16 + l16][kk + quad * 8];
            bf16x8 b20 = *(const bf16x8*)&W2s[cw + l16][kk + quad * 8];
            bf16x8 b21 = *(const bf16x8*)&W2s[cw + 16 + l16][kk + quad * 8];
            acc1[0][0] = __builtin_amdgcn_mfma_f32_16x16x32_bf16(aA0, b10, acc1[0][0], 0, 0, 0);
            acc1[0][1] = __builtin_amdgcn_mfma_f32_16x16x32_bf16(aA0, b11, acc1[0][1], 0, 0, 0);
            acc1[1][0] = __builtin_amdgcn_mfma_f32_16x16x32_bf16(aA1, b10, acc1[1][0], 0, 0, 0);
            acc1[1][1] = __builtin_amdgcn_mfma_f32_16x16x32_bf16(aA1, b11, acc1[1][1], 0, 0, 0);
            acc2[0][0] = __builtin_amdgcn_mfma_f32_16x16x32_bf16(aA0, b20, acc2[0][0], 0, 0, 0);
            acc2[0][1] = __builtin_amdgcn_mfma_f32_16x16x32_bf16(aA0, b21, acc2[0][1], 0, 0, 0);
            acc2[1][0] = __builtin_amdgcn_mfma_f32_16x16x32_bf16(aA1, b20, acc2[1][0], 0, 0, 0);
            acc2[1][1] = __builtin_amdgcn_mfma_f32_16x16x32_bf16(aA1, b21, acc2[1][1], 0, 0, 0);
        }
    }

    #pragma unroll
    for (int ag = 0; ag < 2; ++ag)
        #pragma unroll
        for (int cg = 0; cg < 2; ++cg)
            #pragma unroll
            for (int i = 0; i < 4; ++i)
                C1[(size_t)(r0 + rw + ag * 16 + quad * 4 + i) * 256
                   + c0 + cw + cg * 16 + l16] = f2bf(acc1[ag][cg][i]);

    if (!trans2) {
        #pragma unroll
        for (int ag = 0; ag < 2; ++ag)
            #pragma unroll
            for (int cg = 0; cg < 2; ++cg)
                #pragma unroll
                for (int i = 0; i < 4; ++i)
                    C2[(size_t)(r0 + rw + ag * 16 + quad * 4 + i) * 256
                       + c0 + cw + cg * 16 + l16] = f2bf(acc2[ag][cg][i]);
    } else {
        __syncthreads();
        #pragma unroll
        for (int ag = 0; ag < 2; ++ag)
            #pragma unroll
            for (int cg = 0; cg < 2; ++cg)
                #pragma unroll
                for (int i = 0; i < 4; ++i)
                    W2s[cw + cg * 16 + l16][rw + ag * 16 + quad * 4 + i] = f2bf(acc2[ag][cg][i]);
        __syncthreads();
        const int col = tid >> 2;
        const int seg = (tid & 3) * 16;
        #pragma unroll
        for (int j = 0; j < 2; ++j)
            *(uint4*)(C2 + (size_t)(c0 + col) * nrows + r0 + seg + j * 8) =
                *(const uint4*)&W2s[col][seg + j * 8];
    }
}

// -------- KF row stats (kv stores variance + 0.03 pre-folded) ----------------
__global__ __launch_bounds__(256) void row_stats_kf(
    const ushort* __restrict__ KFb, float* __restrict__ km, float* __restrict__ kv)
{
    const int row  = blockIdx.x * 4 + (threadIdx.x >> 6);
    const int lane = threadIdx.x & 63;
    ushort4 u = *(const ushort4*)(KFb + (size_t)row * 256 + lane * 4);
    float a = bf2f(u.x), b = bf2f(u.y), c = bf2f(u.z), d = bf2f(u.w);
    float s  = a + b + c + d;
    float ss = a * a + b * b + c * c + d * d;
    #pragma unroll
    for (int off = 32; off > 0; off >>= 1) {
        s  += __shfl_down(s, off);
        ss += __shfl_down(ss, off);
    }
    if (lane == 0) {
        float m = s * (1.f / 256.f);
        km[row] = m;
        kv[row] = (ss - 256.f * m * m) * (1.f / 255.f) + 0.03f;
    }
}

// ---------------- fused attention: 8w/16q + XCD-clustered halves ------------------
// r6 proved the occupancy lever (16 waves/CU) but exposed L2-miss traffic: 784 blocks
// re-read the 4MB K/V set 98x (392MB demand); random section->XCD placement makes the
// per-XCD working set 4MB (=L2) and the write stream evicts it -> FETCH 233MB, 2.2TB/s.
// THIS ROUND (single change): cluster halves on XCDs. XCD k = blockIdx%8 (round-robin
// dispatch) serves only half k&3, both branches -> per-XCD K/V set = 4 x 256KB = 1MB,
// L2-resident. Stage glds hit L2; HBM traffic collapses. Q loads nontemporal (49MB
// read-once stream; don't evict K/V). Pipeline = r3/r6's proven single-syncthreads
// schedule. Swizzle identical to r1/r3/r6 (verified).
#define STAGE_TILE(b, ti)                                                     \
    {                                                                         \
        const ushort* kp_ = kp0 + (size_t)(ti) * 32 * DM;                     \
        const ushort* vp_ = vp0 + (ti) * 32;                                  \
        ushort* dst_ = SMu + (b) * 16384;                                     \
        _Pragma("unroll")                                                     \
        for (int p = 0; p < 2; ++p) {                                         \
            int db = (wv * 2 + p) * 512;                                      \
            glds16(kp_ + offK[p], dst_ + db);                                 \
            glds16(vp_ + offV[p], dst_ + 8192 + db);                          \
        }                                                                     \
    }

__global__ __launch_bounds__(512, 4) void fused_attn_8w(
    const ushort* __restrict__ Qb,  const ushort* __restrict__ QFb,
    const ushort* __restrict__ Kb,  const ushort* __restrict__ KFb,
    const ushort* __restrict__ Vtb, const ushort* __restrict__ VFtb,
    const float* __restrict__ km_, const float* __restrict__ kv_,
    float* __restrict__ part, float* __restrict__ denp)
{
    __shared__ ushort SMu[32768];   // 64KB: buf{0,1} x {K 16KB, Vt 16KB}

    const int tid  = threadIdx.x;
    const int wv   = tid >> 6;          // 0..7
    const int lane = tid & 63;
    const int quad = lane >> 4;
    const int l16  = lane & 15;

    // XCD clustering: XCD = blockIdx%8 serves half = (blockIdx&7)&3 only.
    // j = blockIdx>>3 enumerates (br, qc-halfrange); sp (heavier) at low j
    // -> dispatched first. Coverage: each (br,half,qc) exactly once.
    const int k8   = blockIdx.x & 7;
    const int j    = blockIdx.x >> 3;            // 0..97
    const int br   = (j < 49) ? 1 : 0;
    const int half = k8 & 3;
    const int qc   = (k8 >> 2) * 49 + (br ? j : j - 49);   // 0..97
    const int q0   = qc * 128;
    const int kbase = half * 512;
    const int NT   = 16;

    const ushort* qsrc = br ? QFb : Qb;
    const ushort* Ksel = br ? KFb : Kb;
    const ushort* Vsel = br ? VFtb : Vtb;

    // one 16-query group per wave (read-once stream: nontemporal)
    bf16x8 aQ[8];
    {
        const ushort* qp = qsrc + (size_t)(q0 + wv * 16 + l16) * DM + quad * 8;
        #pragma unroll
        for (int s = 0; s < 8; ++s)
            aQ[s] = __builtin_nontemporal_load((const bf16x8*)(qp + s * 32));
    }

    float qmv = 0.f, qvv = 0.f, qm2 = 0.f;
    if (br) {
        float sum = 0.f, ss = 0.f;
        #pragma unroll
        for (int s = 0; s < 8; ++s)
            #pragma unroll
            for (int jj = 0; jj < 8; ++jj) {
                float v = (float)aQ[s][jj];
                sum += v; ss += v * v;
            }
        sum += __shfl_xor(sum, 16, 64); sum += __shfl_xor(sum, 32, 64);
        ss  += __shfl_xor(ss, 16, 64);  ss  += __shfl_xor(ss, 32, 64);
        qmv = sum * (1.f / 256.f);
        qvv = (ss - 256.f * qmv * qmv) * (1.f / 255.f);
        qm2 = qmv * qmv + 0.01f;
    }

    int offK[2], offV[2];
    #pragma unroll
    for (int p = 0; p < 2; ++p) {
        int jw = wv * 2 + p;                 // 0..15
        int Rk = 2 * jw + (lane >> 5);       // 0..31
        int rk = (Rk & 3) + ((Rk >> 4) & 1) * 4 + ((Rk >> 2) & 3) * 8;   // prinv
        int ck = (lane & 31) ^ (Rk & 7);
        offK[p] = rk * DM + ck * 8;
        int Rv = 16 * jw + (lane >> 2);      // 0..255
        int cv = (lane & 3) ^ (Rv & 3);
        offV[p] = Rv * MM + cv * 8;
    }

    const ushort* kp0 = Ksel + (size_t)kbase * DM;
    const ushort* vp0 = Vsel + kbase;

    floatx4 acc[16];
    #pragma unroll
    for (int t = 0; t < 16; ++t) acc[t] = (floatx4){0.f, 0.f, 0.f, 0.f};
    float den = 0.f;
    const int ksw  = l16 & 7;
    const int vswo = (quad ^ (l16 & 3)) * 8;

    STAGE_TILE(0, 0);
    __syncthreads();

    int buf = 0;
    for (int ti = 0; ti < NT; ++ti) {
        if (ti + 1 < NT) STAGE_TILE(buf ^ 1, ti + 1);   // issue-early, wait-late

        const ushort* Ks = SMu + buf * 16384;
        const ushort* Vs = Ks + 8192;

        floatx4 S0 = (floatx4){0.f, 0.f, 0.f, 0.f};
        floatx4 S1 = (floatx4){0.f, 0.f, 0.f, 0.f};
        #pragma unroll
        for (int s = 0; s < 8; ++s) {
            int off = ((s * 4 + quad) ^ ksw) * 8;
            bf16x8 aK0 = *(const bf16x8*)(Ks + l16 * DM + off);
            bf16x8 aK1 = *(const bf16x8*)(Ks + 4096 + l16 * DM + off);
            S0 = __builtin_amdgcn_mfma_f32_16x16x32_bf16(aK0, aQ[s], S0, 0, 0, 0);
            S1 = __builtin_amdgcn_mfma_f32_16x16x32_bf16(aK1, aQ[s], S1, 0, 0, 0);
        }

        const int kk = kbase + ti * 32;
        float pb[8];
        if (!br) {
            #pragma unroll
            for (int r = 0; r < 4; ++r) {
                pb[r]     = __expf(S0[r] * 0.0625f);
                pb[4 + r] = __expf(S1[r] * 0.0625f);
            }
        } else {
            floatx4 km0 = *(const floatx4*)(km_ + kk + 8 * quad);
            floatx4 km1 = *(const floatx4*)(km_ + kk + 8 * quad + 4);
            floatx4 kv0 = *(const floatx4*)(kv_ + kk + 8 * quad);
            floatx4 kv1 = *(const floatx4*)(kv_ + kk + 8 * quad + 4);
            #pragma unroll
            for (int r = 0; r < 4; ++r) {
                {
                    float kmr = km0[r];
                    float mp  = qmv * kmr;
                    float cov = (S0[r] - 256.f * mp) * (1.f / 255.f);
                    float num = (2.f * mp + 0.01f) * (2.f * cov + 0.03f);
                    float dn  = (qm2 + kmr * kmr) * (qvv + kv0[r]) + 1e-8f;
                    pb[r] = __expf(num / dn);
                }
                {
                    float kmr = km1[r];
                    float mp  = qmv * kmr;
                    float cov = (S1[r] - 256.f * mp) * (1.f / 255.f);
                    float num = (2.f * mp + 0.01f) * (2.f * cov + 0.03f);
                    float dn  = (qm2 + kmr * kmr) * (qvv + kv1[r]) + 1e-8f;
                    pb[4 + r] = __expf(num / dn);
                }
            }
        }
        union { __bf16 h[8]; bf16x8 v; } ap;
        #pragma unroll
        for (int jj = 0; jj < 8; ++jj) {
            den += pb[jj];
            ap.h[jj] = (__bf16)pb[jj];
        }

        #pragma unroll
        for (int t = 0; t < 16; ++t) {
            bf16x8 bV = *(const bf16x8*)(Vs + (t * 16 + l16) * 32 + vswo);
            acc[t] = __builtin_amdgcn_mfma_f32_16x16x32_bf16(ap.v, bV, acc[t], 0, 0, 0);
        }

        __syncthreads();   // drains vmcnt(0): prefetch had full compute phase to land
        buf ^= 1;
    }

    den += __shfl_xor(den, 16, 64);
    den += __shfl_xor(den, 32, 64);

    const int sec = br * 4 + half;
    float* Np = part + (size_t)sec * ((size_t)NBQ * DM);
    #pragma unroll
    for (int t = 0; t < 16; ++t)
        #pragma unroll
        for (int r = 0; r < 4; ++r) {
            int row = q0 + wv * 16 + quad * 4 + r;
            Np[(size_t)row * DM + t * 16 + l16] = acc[t][r];
        }
    if (lane < 16)
        denp[(size_t)sec * NBQ + q0 + wv * 16 + lane] = den;
}

// ---------------- fallback (r1-proven serial kernel, direct out; small ws) --------
__global__ __launch_bounds__(256, 2) void fused_attn_fb(
    const ushort* __restrict__ Qb,  const ushort* __restrict__ QFb,
    const ushort* __restrict__ Kb,  const ushort* __restrict__ KFb,
    const ushort* __restrict__ Vtb, const ushort* __restrict__ VFtb,
    const float* __restrict__ km_, const float* __restrict__ kv_,
    float* __restrict__ out)
{
    __shared__ ushort SMu[32768];
    float* combuf = (float*)SMu;

    const int tid  = threadIdx.x;
    const int wv   = tid >> 6;
    const int lane = tid & 63;
    const int quad = lane >> 4;
    const int l16  = lane & 15;
    const int qsel = wv & 1;
    const int br   = wv >> 1;
    const int q0   = blockIdx.x * 32;

    const ushort* qsrc = br ? QFb : Qb;
    bf16x8 aQ[8];
    {
        const ushort* qp = qsrc + (size_t)(q0 + qsel * 16 + l16) * DM + quad * 8;
        #pragma unroll
        for (int s = 0; s < 8; ++s) aQ[s] = *(const bf16x8*)(qp + s * 32);
    }

    float qmv = 0.f, qvv = 0.f, qm2 = 0.f;
    if (br) {
        float sum = 0.f, ss = 0.f;
        #pragma unroll
        for (int s = 0; s < 8; ++s)
            #pragma unroll
            for (int jj = 0; jj < 8; ++jj) {
                float v = (float)aQ[s][jj];
                sum += v; ss += v * v;
            }
        sum += __shfl_xor(sum, 16, 64); sum += __shfl_xor(sum, 32, 64);
        ss  += __shfl_xor(ss, 16, 64);  ss  += __shfl_xor(ss, 32, 64);
        qmv = sum * (1.f / 256.f);
        qvv = (ss - 256.f * qmv * qmv) * (1.f / 255.f);
        qm2 = qmv * qmv + 0.01f;
    }

    int offK[4], offV[4];
    #pragma unroll
    for (int p = 0; p < 4; ++p) {
        int jw = wv * 4 + p;
        int Rk = 2 * jw + (lane >> 5);
        int rk = (Rk & 3) + ((Rk >> 4) & 1) * 4 + ((Rk >> 2) & 3) * 8;
        int ck = (lane & 31) ^ (Rk & 7);
        offK[p] = rk * DM + ck * 8;
        int Rv = 16 * jw + (lane >> 2);
        int cv = (lane & 3) ^ (Rv & 3);
        offV[p] = Rv * MM + cv * 8;
    }

    const ushort* kp  = Kb;
    const ushort* kfp = KFb;
    const ushort* vp  = Vtb;
    const ushort* vfp = VFtb;

    floatx4 acc[16];
    #pragma unroll
    for (int t = 0; t < 16; ++t) acc[t] = (floatx4){0.f, 0.f, 0.f, 0.f};
    float den = 0.f;

    const int ksw  = l16 & 7;
    const int vswo = (quad ^ (l16 & 3)) * 8;

    for (int kt = 0; kt < MM; kt += 32) {
        __syncthreads();
        #pragma unroll
        for (int p = 0; p < 4; ++p) {
            int db = (wv * 4 + p) * 512;
            glds16(kp  + offK[p], SMu + db);
            glds16(kfp + offK[p], SMu + 8192 + db);
            glds16(vp  + offV[p], SMu + 16384 + db);
            glds16(vfp + offV[p], SMu + 24576 + db);
        }
        kp += 32 * DM; kfp += 32 * DM; vp += 32; vfp += 32;
        __syncthreads();

        const ushort* Ks = SMu + (br ? 8192 : 0);
        floatx4 S0 = (floatx4){0.f, 0.f, 0.f, 0.f};
        floatx4 S1 = (floatx4){0.f, 0.f, 0.f, 0.f};
        #pragma unroll
        for (int s = 0; s < 8; ++s) {
            int off = ((s * 4 + quad) ^ ksw) * 8;
            bf16x8 aK0 = *(const bf16x8*)(Ks + l16 * DM + off);
            bf16x8 aK1 = *(const bf16x8*)(Ks + 4096 + l16 * DM + off);
            S0 = __builtin_amdgcn_mfma_f32_16x16x32_bf16(aK0, aQ[s], S0, 0, 0, 0);
            S1 = __builtin_amdgcn_mfma_f32_16x16x32_bf16(aK1, aQ[s], S1, 0, 0, 0);
        }

        float pb[8];
        if (!br) {
            #pragma unroll
            for (int r = 0; r < 4; ++r) {
                pb[r]     = __expf(S0[r] * 0.0625f);
                pb[4 + r] = __expf(S1[r] * 0.0625f);
            }
        } else {
            floatx4 km0 = *(const floatx4*)(km_ + kt + 8 * quad);
            floatx4 km1 = *(const floatx4*)(km_ + kt + 8 * quad + 4);
            floatx4 kv0 = *(const floatx4*)(kv_ + kt + 8 * quad);
            floatx4 kv1 = *(const floatx4*)(kv_ + kt + 8 * quad + 4);
            #pragma unroll
            for (int r = 0; r < 4; ++r) {
                {
                    float kmr = km0[r];
                    float mp  = qmv * kmr;
                    float cov = (S0[r] - 256.f * mp) * (1.f / 255.f);
                    float num = (2.f * mp + 0.01f) * (2.f * cov + 0.03f);
                    float dn  = (qm2 + kmr * kmr) * (qvv + kv0[r]) + 1e-8f;
                    pb[r] = __expf(num / dn);
                }
                {
                    float kmr = km1[r];
                    float mp  = qmv * kmr;
                    float cov = (S1[r] - 256.f * mp) * (1.f / 255.f);
                    float num = (2.f * mp + 0.01f) * (2.f * cov + 0.03f);
                    float dn  = (qm2 + kmr * kmr) * (qvv + kv1[r]) + 1e-8f;
                    pb[4 + r] = __expf(num / dn);
                }
            }
        }
        union { __bf16 h[8]; bf16x8 v; } ap;
        #pragma unroll
        for (int jj = 0; jj < 8; ++jj) {
            den += pb[jj];
            ap.h[jj] = (__bf16)pb[jj];
        }

        const ushort* Vs = SMu + (br ? 24576 : 16384);
        #pragma unroll
        for (int t = 0; t < 16; ++t) {
            bf16x8 bV = *(const bf16x8*)(Vs + (t * 16 + l16) * 32 + vswo);
            acc[t] = __builtin_amdgcn_mfma_f32_16x16x32_bf16(ap.v, bV, acc[t], 0, 0, 0);
        }
    }

    den += __shfl_xor(den, 16, 64);
    den += __shfl_xor(den, 32, 64);
    float rdn[4];
    #pragma unroll
    for (int r = 0; r < 4; ++r)
        rdn[r] = 1.f / __shfl(den, quad * 4 + r, 64);

    __syncthreads();
    if (br) {
        #pragma unroll
        for (int t = 0; t < 16; ++t)
            #pragma unroll
            for (int r = 0; r < 4; ++r)
                combuf[(qsel * 16 + quad * 4 + r) * 256 + t * 16 + l16] = acc[t][r] * rdn[r];
    }
    __syncthreads();
    if (!br) {
        #pragma unroll
        for (int t = 0; t < 16; ++t)
            #pragma unroll
            for (int r = 0; r < 4; ++r) {
                int ql = qsel * 16 + quad * 4 + r;
                out[(size_t)(q0 + ql) * DM + t * 16 + l16] =
                    acc[t][r] * rdn[r] + combuf[ql * 256 + t * 16 + l16];
            }
    }
}

// ---------------- combine the MEM-quarters (per-branch normalize, sum) ----------
__global__ __launch_bounds__(256) void combine_halves(
    const float* __restrict__ part, const float* __restrict__ denp,
    float* __restrict__ out)
{
    const size_t stride = (size_t)NBQ * 64;         // floatx4 units per section
    const floatx4* p4 = (const floatx4*)part;
    floatx4* o4 = (floatx4*)out;
    #pragma unroll
    for (int u = 0; u < 2; ++u) {
        size_t i = (size_t)blockIdx.x * 512 + (size_t)u * 256 + threadIdx.x;
        int q = (int)(i >> 6);
        float dc = 0.f, ds = 0.f;
        #pragma unroll
        for (int h = 0; h < 4; ++h) {
            dc += denp[(size_t)h * NBQ + q];
            ds += denp[(size_t)(4 + h) * NBQ + q];
        }
        float rc = 1.f / dc, rs = 1.f / ds;
        floatx4 nc = {0.f, 0.f, 0.f, 0.f}, ns = {0.f, 0.f, 0.f, 0.f};
        #pragma unroll
        for (int h = 0; h < 4; ++h) {
            floatx4 c = __builtin_nontemporal_load(&p4[(size_t)h * stride + i]);
            floatx4 s = __builtin_nontemporal_load(&p4[(size_t)(4 + h) * stride + i]);
            nc += c;
            ns += s;
        }
        o4[i] = nc * rc + ns * rs;
    }
}

extern "C" void kernel_launch(void* const* d_in, const int* in_sizes, int n_in,
                              void* d_out, int out_size, void* d_ws, size_t ws_size,
                              hipStream_t stream)
{
    const float* x      = (const float*)d_in[0];
    const float* ch_mem = (const float*)d_in[1];
    const float* ch_wq  = (const float*)d_in[2];
    const float* ch_wk  = (const float*)d_in[3];
    const float* ch_wv  = (const float*)d_in[4];
    const float* sp_mem = (const float*)d_in[5];
    const float* sp_wq  = (const float*)d_in[6];
    const float* sp_wk  = (const float*)d_in[7];
    const float* sp_wv  = (const float*)d_in[8];
    float* out = (float*)d_out;

    ushort* Qb   = (ushort*)d_ws;                 // [12544][256]
    ushort* QFb  = Qb   + (size_t)NBQ * DM;
    ushort* Kb   = QFb  + (size_t)NBQ * DM;       // [2048][256]
    ushort* KFb  = Kb   + (size_t)MM * DM;
    ushort* Vtb  = KFb  + (size_t)MM * DM;        // [256][2048] transposed
    ushort* VFtb = Vtb  + (size_t)MM * DM;
    float*  km   = (float*)(VFtb + (size_t)MM * DM);
    float*  kv   = km + MM;
    float*  denp = kv + MM;                       // 8 sections x [12544]
    float*  part = denp + (size_t)8 * NBQ;        // 8 x [12544][256] f32

    const size_t base_b = (size_t)((char*)part - (char*)d_ws);
    const size_t need4  = base_b + (size_t)8 * NBQ * DM * sizeof(float);

    dim3 blk(256);
    gemm_proj_all<<<dim3(1040), blk, 0, stream>>>(
        x, ch_mem, ch_wq, ch_wk, ch_wv, sp_mem, sp_wq, sp_wk, sp_wv,
        Qb, QFb, Kb, KFb, Vtb, VFtb);
    row_stats_kf<<<dim3(MM / 4), blk, 0, stream>>>(KFb, km, kv);
    if (ws_size >= need4) {
        fused_attn_8w<<<dim3(784), dim3(512), 0, stream>>>(
            Qb, QFb, Kb, KFb, Vtb, VFtb, km, kv, part, denp);
        combine_halves<<<dim3(NBQ * DM / 4 / 512), blk, 0, stream>>>(part, denp, out);
    } else {
        fused_attn_fb<<<dim3(NBQ / 32), blk, 0, stream>>>(
            Qb, QFb, Kb, KFb, Vtb, VFtb, km, kv, out);
    }
}

// Round 9
// 291.697 us; speedup vs baseline: 1.0050x; 1.0050x over previous
//
#include <hip/hip_runtime.h>

#define NBQ 12544
#define DM  256
#define MM  2048

typedef __attribute__((ext_vector_type(8)))  __bf16 bf16x8;
typedef __attribute__((ext_vector_type(4)))  float  floatx4;

__device__ __forceinline__ ushort f2bf(float x) {
    unsigned u = __float_as_uint(x);
    u += 0x7fffu + ((u >> 16) & 1u);   // RNE
    return (ushort)(u >> 16);
}
__device__ __forceinline__ float bf2f(ushort h) {
    return __uint_as_float(((unsigned)h) << 16);
}
__device__ __forceinline__ ushort4 cvt4(float4 f) {   // HW bf16 cvt (RNE, = f2bf)
    union { __bf16 h[4]; ushort4 u; } r;
    r.h[0] = (__bf16)f.x; r.h[1] = (__bf16)f.y;
    r.h[2] = (__bf16)f.z; r.h[3] = (__bf16)f.w;
    return r.u;
}

// async global->LDS, 16B per lane; dest = wave-uniform base + lane*16
__device__ __forceinline__ void glds16(const ushort* g, ushort* l) {
    __builtin_amdgcn_global_load_lds(
        (const __attribute__((address_space(1))) unsigned int*)g,
        (__attribute__((address_space(3))) unsigned int*)l, 16, 0, 0);
}

// ---------- projections, weight-pairs folded; 2-phase reg prefetch ----------
__global__ __launch_bounds__(256) void gemm_proj_all(
    const float* __restrict__ x,      const float* __restrict__ ch_mem,
    const float* __restrict__ ch_wq,  const float* __restrict__ ch_wk,
    const float* __restrict__ ch_wv,  const float* __restrict__ sp_mem,
    const float* __restrict__ sp_wq,  const float* __restrict__ sp_wk,
    const float* __restrict__ sp_wv,
    ushort* __restrict__ Qb,  ushort* __restrict__ QFb,
    ushort* __restrict__ Kb,  ushort* __restrict__ KFb,
    ushort* __restrict__ Vtb, ushort* __restrict__ VFtb)
{
    __shared__ ushort As[64][72];
    __shared__ ushort W1s[64][72];
    __shared__ ushort W2s[64][72];

    int bid = blockIdx.x;
    const float* A; const float* W1; const float* W2;
    ushort* C1; ushort* C2; int nrows, trans2;
    if (bid < 784) {
        A = x; W1 = ch_wq; W2 = sp_wq; C1 = Qb; C2 = QFb; nrows = NBQ; trans2 = 0;
    } else if (bid < 912) {
        A = ch_mem; W1 = ch_wk; W2 = ch_wv; C1 = Kb; C2 = Vtb;
        nrows = MM; trans2 = 1; bid -= 784;
    } else {
        A = sp_mem; W1 = sp_wk; W2 = sp_wv; C1 = KFb; C2 = VFtb;
        nrows = MM; trans2 = 1; bid -= 912;
    }
    const int r0 = (bid >> 2) * 64;
    const int c0 = (bid & 3) * 64;

    const int tid  = threadIdx.x;
    const int wv   = tid >> 6;
    const int lane = tid & 63;
    const int quad = lane >> 4;
    const int l16  = lane & 15;
    const int rw = (wv & 1) * 32;
    const int cw = (wv >> 1) * 32;

    floatx4 acc1[2][2], acc2[2][2];
    #pragma unroll
    for (int i = 0; i < 2; ++i)
        #pragma unroll
        for (int j = 0; j < 2; ++j) {
            acc1[i][j] = (floatx4){0.f, 0.f, 0.f, 0.f};
            acc2[i][j] = (floatx4){0.f, 0.f, 0.f, 0.f};
        }

    float4 a4[4], w14[4], w24[4];
    #pragma unroll
    for (int it = 0; it < 4; ++it) {
        int idx = tid + it * 256;
        int r = idx >> 4, c4 = (idx & 15) * 4;
        a4[it]  = *(const float4*)(A  + (size_t)(r0 + r) * 256 + c4);
        w14[it] = *(const float4*)(W1 + (size_t)(c0 + r) * 256 + c4);
        w24[it] = *(const float4*)(W2 + (size_t)(c0 + r) * 256 + c4);
    }

    for (int d0 = 0; d0 < 256; d0 += 64) {
        __syncthreads();
        #pragma unroll
        for (int it = 0; it < 4; ++it) {
            int idx = tid + it * 256;
            int r = idx >> 4, c4 = (idx & 15) * 4;
            *(ushort4*)&As[r][c4]  = cvt4(a4[it]);
            *(ushort4*)&W1s[r][c4] = cvt4(w14[it]);
            *(ushort4*)&W2s[r][c4] = cvt4(w24[it]);
        }
        if (d0 + 64 < 256) {
            #pragma unroll
            for (int it = 0; it < 4; ++it) {
                int idx = tid + it * 256;
                int r = idx >> 4, c4 = (idx & 15) * 4;
                a4[it]  = *(const float4*)(A  + (size_t)(r0 + r) * 256 + d0 + 64 + c4);
                w14[it] = *(const float4*)(W1 + (size_t)(c0 + r) * 256 + d0 + 64 + c4);
                w24[it] = *(const float4*)(W2 + (size_t)(c0 + r) * 256 + d0 + 64 + c4);
            }
        }
        __syncthreads();
        #pragma unroll
        for (int kk = 0; kk < 64; kk += 32) {
            bf16x8 aA0 = *(const bf16x8*)&As[rw + l16][kk + quad * 8];
            bf16x8 aA1 = *(const bf16x8*)&As[rw + 16 + l16][kk + quad * 8];
            bf16x8 b10 = *(const bf16x8*)&W1s[cw + l16][kk + quad * 8];
            bf16x8 b11 = *(const bf16x8*)&W1s[cw + 16 + l16][kk + quad * 8];
            bf16x8 b20 = *(const bf16x8*)&W2s[cw + l16][kk + quad * 8];
            bf16x8 b21 = *(const bf16x8*)&W2s[cw + 16 + l16][kk + quad * 8];
            acc1[0][0] = __builtin_amdgcn_mfma_f32_16x16x32_bf16(aA0, b10, acc1[0][0], 0, 0, 0);
            acc1[0][1] = __builtin_amdgcn_mfma_f32_16x16x32_bf16(aA0, b11, acc1[0][1], 0, 0, 0);
            acc1[1][0] = __builtin_amdgcn_mfma_f32_16x16x32_bf16(aA1, b10, acc1[1][0], 0, 0, 0);
            acc1[1][1] = __builtin_amdgcn_mfma_f32_16x16x32_bf16(aA1, b11, acc1[1][1], 0, 0, 0);
            acc2[0][0] = __builtin_amdgcn_mfma_f32_16x16x32_bf16(aA0, b20, acc2[0][0], 0, 0, 0);
            acc2[0][1] = __builtin_amdgcn_mfma_f32_16x16x32_bf16(aA0, b21, acc2[0][1], 0, 0, 0);
            acc2[1][0] = __builtin_amdgcn_mfma_f32_16x16x32_bf16(aA1, b20, acc2[1][0], 0, 0, 0);
            acc2[1][1] = __builtin_amdgcn_mfma_f32_16x16x32_bf16(aA1, b21, acc2[1][1], 0, 0, 0);
        }
    }

    #pragma unroll
    for (int ag = 0; ag < 2; ++ag)
        #pragma unroll
        for (int cg = 0; cg < 2; ++cg)
            #pragma unroll
            for (int i = 0; i < 4; ++i)
                C1[(size_t)(r0 + rw + ag * 16 + quad * 4 + i) * 256
                   + c0 + cw + cg * 16 + l16] = f2bf(acc1[ag][cg][i]);

    if (!trans2) {
        #pragma unroll
        for (int ag = 0; ag < 2; ++ag)
            #pragma unroll
            for (int cg = 0; cg < 2; ++cg)
                #pragma unroll
                for (int i = 0; i < 4; ++i)
                    C2[(size_t)(r0 + rw + ag * 16 + quad * 4 + i) * 256
                       + c0 + cw + cg * 16 + l16] = f2bf(acc2[ag][cg][i]);
    } else {
        __syncthreads();
        #pragma unroll
        for (int ag = 0; ag < 2; ++ag)
            #pragma unroll
            for (int cg = 0; cg < 2; ++cg)
                #pragma unroll
                for (int i = 0; i < 4; ++i)
                    W2s[cw + cg * 16 + l16][rw + ag * 16 + quad * 4 + i] = f2bf(acc2[ag][cg][i]);
        __syncthreads();
        const int col = tid >> 2;
        const int seg = (tid & 3) * 16;
        #pragma unroll
        for (int j = 0; j < 2; ++j)
            *(uint4*)(C2 + (size_t)(c0 + col) * nrows + r0 + seg + j * 8) =
                *(const uint4*)&W2s[col][seg + j * 8];
    }
}

// -------- KF row stats (kv stores variance + 0.03 pre-folded) ----------------
__global__ __launch_bounds__(256) void row_stats_kf(
    const ushort* __restrict__ KFb, float* __restrict__ km, float* __restrict__ kv)
{
    const int row  = blockIdx.x * 4 + (threadIdx.x >> 6);
    const int lane = threadIdx.x & 63;
    ushort4 u = *(const ushort4*)(KFb + (size_t)row * 256 + lane * 4);
    float a = bf2f(u.x), b = bf2f(u.y), c = bf2f(u.z), d = bf2f(u.w);
    float s  = a + b + c + d;
    float ss = a * a + b * b + c * c + d * d;
    #pragma unroll
    for (int off = 32; off > 0; off >>= 1) {
        s  += __shfl_down(s, off);
        ss += __shfl_down(ss, off);
    }
    if (lane == 0) {
        float m = s * (1.f / 256.f);
        km[row] = m;
        kv[row] = (ss - 256.f * m * m) * (1.f / 255.f) + 0.03f;
    }
}

// ---------------- fused attention: 16-wave blocks (256q), NH=4 MEM-split ----------
// r6/r7 traffic identity: dur = (FETCH+WRITE)/realized-BW; stage demand scales as
// 1/BQ (2*(NBQ/BQ)*2MB). Single change vs r6: BQ 128->256 via 1024-thread blocks
// (16 waves x 16q). Per-wave body identical (measured 64 VGPR -> 8 waves/SIMD ok),
// LDS unchanged 64KB dbuf -> 2 blocks/CU -> up to 32 waves/CU. Grid 392, all
// co-resident at t=0. Demand 392->196MB. XCD clustering dropped (r7 falsified it:
// FETCH -20% only, dur flat). Pipeline = proven single-syncthreads schedule.
// Swizzle identical to r1/r3/r6 (verified).
#define STAGE_TILE(b, ti)                                                     \
    {                                                                         \
        const ushort* kp_ = kp0 + (size_t)(ti) * 32 * DM;                     \
        const ushort* vp_ = vp0 + (ti) * 32;                                  \
        ushort* dst_ = SMu + (b) * 16384;                                     \
        glds16(kp_ + offK, dst_ + wv * 512);                                  \
        glds16(vp_ + offV, dst_ + 8192 + wv * 512);                           \
    }

__global__ __launch_bounds__(1024, 2) void fused_attn_16w(
    const ushort* __restrict__ Qb,  const ushort* __restrict__ QFb,
    const ushort* __restrict__ Kb,  const ushort* __restrict__ KFb,
    const ushort* __restrict__ Vtb, const ushort* __restrict__ VFtb,
    const float* __restrict__ km_, const float* __restrict__ kv_,
    float* __restrict__ part, float* __restrict__ denp)
{
    __shared__ ushort SMu[32768];   // 64KB: buf{0,1} x {K 16KB, Vt 16KB}

    const int tid  = threadIdx.x;
    const int wv   = tid >> 6;          // 0..15
    const int lane = tid & 63;
    const int quad = lane >> 4;
    const int l16  = lane & 15;

    // grid 392 = 2 br x 4 half x 49 qchunks; sp first (heavier)
    int bid = blockIdx.x;
    const int br  = (bid < 196) ? 1 : 0;
    int rem = br ? bid : bid - 196;
    const int half = rem / 49;
    const int qc   = rem - half * 49;            // 0..48
    const int q0   = qc * 256;
    const int kbase = half * 512;
    const int NT   = 16;

    const ushort* qsrc = br ? QFb : Qb;
    const ushort* Ksel = br ? KFb : Kb;
    const ushort* Vsel = br ? VFtb : Vtb;

    // one 16-query group per wave (read-once stream: nontemporal)
    bf16x8 aQ[8];
    {
        const ushort* qp = qsrc + (size_t)(q0 + wv * 16 + l16) * DM + quad * 8;
        #pragma unroll
        for (int s = 0; s < 8; ++s)
            aQ[s] = __builtin_nontemporal_load((const bf16x8*)(qp + s * 32));
    }

    float qmv = 0.f, qvv = 0.f, qm2 = 0.f;
    if (br) {
        float sum = 0.f, ss = 0.f;
        #pragma unroll
        for (int s = 0; s < 8; ++s)
            #pragma unroll
            for (int jj = 0; jj < 8; ++jj) {
                float v = (float)aQ[s][jj];
                sum += v; ss += v * v;
            }
        sum += __shfl_xor(sum, 16, 64); sum += __shfl_xor(sum, 32, 64);
        ss  += __shfl_xor(ss, 16, 64);  ss  += __shfl_xor(ss, 32, 64);
        qmv = sum * (1.f / 256.f);
        qvv = (ss - 256.f * qmv * qmv) * (1.f / 255.f);
        qm2 = qmv * qmv + 0.01f;
    }

    // staging source offsets: wave wv covers chunk jw = wv of the 16KB tile
    int offK, offV;
    {
        int jw = wv;                         // 0..15
        int Rk = 2 * jw + (lane >> 5);       // 0..31
        int rk = (Rk & 3) + ((Rk >> 4) & 1) * 4 + ((Rk >> 2) & 3) * 8;   // prinv
        int ck = (lane & 31) ^ (Rk & 7);
        offK = rk * DM + ck * 8;
        int Rv = 16 * jw + (lane >> 2);      // 0..255
        int cv = (lane & 3) ^ (Rv & 3);
        offV = Rv * MM + cv * 8;
    }

    const ushort* kp0 = Ksel + (size_t)kbase * DM;
    const ushort* vp0 = Vsel + kbase;

    floatx4 acc[16];
    #pragma unroll
    for (int t = 0; t < 16; ++t) acc[t] = (floatx4){0.f, 0.f, 0.f, 0.f};
    float den = 0.f;
    const int ksw  = l16 & 7;
    const int vswo = (quad ^ (l16 & 3)) * 8;

    STAGE_TILE(0, 0);
    __syncthreads();

    int buf = 0;
    for (int ti = 0; ti < NT; ++ti) {
        if (ti + 1 < NT) STAGE_TILE(buf ^ 1, ti + 1);   // issue-early, wait-late

        const ushort* Ks = SMu + buf * 16384;
        const ushort* Vs = Ks + 8192;

        floatx4 S0 = (floatx4){0.f, 0.f, 0.f, 0.f};
        floatx4 S1 = (floatx4){0.f, 0.f, 0.f, 0.f};
        #pragma unroll
        for (int s = 0; s < 8; ++s) {
            int off = ((s * 4 + quad) ^ ksw) * 8;
            bf16x8 aK0 = *(const bf16x8*)(Ks + l16 * DM + off);
            bf16x8 aK1 = *(const bf16x8*)(Ks + 4096 + l16 * DM + off);
            S0 = __builtin_amdgcn_mfma_f32_16x16x32_bf16(aK0, aQ[s], S0, 0, 0, 0);
            S1 = __builtin_amdgcn_mfma_f32_16x16x32_bf16(aK1, aQ[s], S1, 0, 0, 0);
        }

        const int kk = kbase + ti * 32;
        float pb[8];
        if (!br) {
            #pragma unroll
            for (int r = 0; r < 4; ++r) {
                pb[r]     = __expf(S0[r] * 0.0625f);
                pb[4 + r] = __expf(S1[r] * 0.0625f);
            }
        } else {
            floatx4 km0 = *(const floatx4*)(km_ + kk + 8 * quad);
            floatx4 km1 = *(const floatx4*)(km_ + kk + 8 * quad + 4);
            floatx4 kv0 = *(const floatx4*)(kv_ + kk + 8 * quad);
            floatx4 kv1 = *(const floatx4*)(kv_ + kk + 8 * quad + 4);
            #pragma unroll
            for (int r = 0; r < 4; ++r) {
                {
                    float kmr = km0[r];
                    float mp  = qmv * kmr;
                    float cov = (S0[r] - 256.f * mp) * (1.f / 255.f);
                    float num = (2.f * mp + 0.01f) * (2.f * cov + 0.03f);
                    float dn  = (qm2 + kmr * kmr) * (qvv + kv0[r]) + 1e-8f;
                    pb[r] = __expf(num / dn);
                }
                {
                    float kmr = km1[r];
                    float mp  = qmv * kmr;
                    float cov = (S1[r] - 256.f * mp) * (1.f / 255.f);
                    float num = (2.f * mp + 0.01f) * (2.f * cov + 0.03f);
                    float dn  = (qm2 + kmr * kmr) * (qvv + kv1[r]) + 1e-8f;
                    pb[4 + r] = __expf(num / dn);
                }
            }
        }
        union { __bf16 h[8]; bf16x8 v; } ap;
        #pragma unroll
        for (int jj = 0; jj < 8; ++jj) {
            den += pb[jj];
            ap.h[jj] = (__bf16)pb[jj];
        }

        #pragma unroll
        for (int t = 0; t < 16; ++t) {
            bf16x8 bV = *(const bf16x8*)(Vs + (t * 16 + l16) * 32 + vswo);
            acc[t] = __builtin_amdgcn_mfma_f32_16x16x32_bf16(ap.v, bV, acc[t], 0, 0, 0);
        }

        __syncthreads();   // drains vmcnt(0): prefetch had full compute phase to land
        buf ^= 1;
    }

    den += __shfl_xor(den, 16, 64);
    den += __shfl_xor(den, 32, 64);

    const int sec = br * 4 + half;
    float* Np = part + (size_t)sec * ((size_t)NBQ * DM);
    #pragma unroll
    for (int t = 0; t < 16; ++t)
        #pragma unroll
        for (int r = 0; r < 4; ++r) {
            int row = q0 + wv * 16 + quad * 4 + r;
            Np[(size_t)row * DM + t * 16 + l16] = acc[t][r];
        }
    if (lane < 16)
        denp[(size_t)sec * NBQ + q0 + wv * 16 + lane] = den;
}

// ---------------- fallback (r1-proven serial kernel, direct out; small ws) --------
__global__ __launch_bounds__(256, 2) void fused_attn_fb(
    const ushort* __restrict__ Qb,  const ushort* __restrict__ QFb,
    const ushort* __restrict__ Kb,  const ushort* __restrict__ KFb,
    const ushort* __restrict__ Vtb, const ushort* __restrict__ VFtb,
    const float* __restrict__ km_, const float* __restrict__ kv_,
    float* __restrict__ out)
{
    __shared__ ushort SMu[32768];
    float* combuf = (float*)SMu;

    const int tid  = threadIdx.x;
    const int wv   = tid >> 6;
    const int lane = tid & 63;
    const int quad = lane >> 4;
    const int l16  = lane & 15;
    const int qsel = wv & 1;
    const int br   = wv >> 1;
    const int q0   = blockIdx.x * 32;

    const ushort* qsrc = br ? QFb : Qb;
    bf16x8 aQ[8];
    {
        const ushort* qp = qsrc + (size_t)(q0 + qsel * 16 + l16) * DM + quad * 8;
        #pragma unroll
        for (int s = 0; s < 8; ++s) aQ[s] = *(const bf16x8*)(qp + s * 32);
    }

    float qmv = 0.f, qvv = 0.f, qm2 = 0.f;
    if (br) {
        float sum = 0.f, ss = 0.f;
        #pragma unroll
        for (int s = 0; s < 8; ++s)
            #pragma unroll
            for (int jj = 0; jj < 8; ++jj) {
                float v = (float)aQ[s][jj];
                sum += v; ss += v * v;
            }
        sum += __shfl_xor(sum, 16, 64); sum += __shfl_xor(sum, 32, 64);
        ss  += __shfl_xor(ss, 16, 64);  ss  += __shfl_xor(ss, 32, 64);
        qmv = sum * (1.f / 256.f);
        qvv = (ss - 256.f * qmv * qmv) * (1.f / 255.f);
        qm2 = qmv * qmv + 0.01f;
    }

    int offK[4], offV[4];
    #pragma unroll
    for (int p = 0; p < 4; ++p) {
        int jw = wv * 4 + p;
        int Rk = 2 * jw + (lane >> 5);
        int rk = (Rk & 3) + ((Rk >> 4) & 1) * 4 + ((Rk >> 2) & 3) * 8;
        int ck = (lane & 31) ^ (Rk & 7);
        offK[p] = rk * DM + ck * 8;
        int Rv = 16 * jw + (lane >> 2);
        int cv = (lane & 3) ^ (Rv & 3);
        offV[p] = Rv * MM + cv * 8;
    }

    const ushort* kp  = Kb;
    const ushort* kfp = KFb;
    const ushort* vp  = Vtb;
    const ushort* vfp = VFtb;

    floatx4 acc[16];
    #pragma unroll
    for (int t = 0; t < 16; ++t) acc[t] = (floatx4){0.f, 0.f, 0.f, 0.f};
    float den = 0.f;

    const int ksw  = l16 & 7;
    const int vswo = (quad ^ (l16 & 3)) * 8;

    for (int kt = 0; kt < MM; kt += 32) {
        __syncthreads();
        #pragma unroll
        for (int p = 0; p < 4; ++p) {
            int db = (wv * 4 + p) * 512;
            glds16(kp  + offK[p], SMu + db);
            glds16(kfp + offK[p], SMu + 8192 + db);
            glds16(vp  + offV[p], SMu + 16384 + db);
            glds16(vfp + offV[p], SMu + 24576 + db);
        }
        kp += 32 * DM; kfp += 32 * DM; vp += 32; vfp += 32;
        __syncthreads();

        const ushort* Ks = SMu + (br ? 8192 : 0);
        floatx4 S0 = (floatx4){0.f, 0.f, 0.f, 0.f};
        floatx4 S1 = (floatx4){0.f, 0.f, 0.f, 0.f};
        #pragma unroll
        for (int s = 0; s < 8; ++s) {
            int off = ((s * 4 + quad) ^ ksw) * 8;
            bf16x8 aK0 = *(const bf16x8*)(Ks + l16 * DM + off);
            bf16x8 aK1 = *(const bf16x8*)(Ks + 4096 + l16 * DM + off);
            S0 = __builtin_amdgcn_mfma_f32_16x16x32_bf16(aK0, aQ[s], S0, 0, 0, 0);
            S1 = __builtin_amdgcn_mfma_f32_16x16x32_bf16(aK1, aQ[s], S1, 0, 0, 0);
        }

        float pb[8];
        if (!br) {
            #pragma unroll
            for (int r = 0; r < 4; ++r) {
                pb[r]     = __expf(S0[r] * 0.0625f);
                pb[4 + r] = __expf(S1[r] * 0.0625f);
            }
        } else {
            floatx4 km0 = *(const floatx4*)(km_ + kt + 8 * quad);
            floatx4 km1 = *(const floatx4*)(km_ + kt + 8 * quad + 4);
            floatx4 kv0 = *(const floatx4*)(kv_ + kt + 8 * quad);
            floatx4 kv1 = *(const floatx4*)(kv_ + kt + 8 * quad + 4);
            #pragma unroll
            for (int r = 0; r < 4; ++r) {
                {
                    float kmr = km0[r];
                    float mp  = qmv * kmr;
                    float cov = (S0[r] - 256.f * mp) * (1.f / 255.f);
                    float num = (2.f * mp + 0.01f) * (2.f * cov + 0.03f);
                    float dn  = (qm2 + kmr * kmr) * (qvv + kv0[r]) + 1e-8f;
                    pb[r] = __expf(num / dn);
                }
                {
                    float kmr = km1[r];
                    float mp  = qmv * kmr;
                    float cov = (S1[r] - 256.f * mp) * (1.f / 255.f);
                    float num = (2.f * mp + 0.01f) * (2.f * cov + 0.03f);
                    float dn  = (qm2 + kmr * kmr) * (qvv + kv1[r]) + 1e-8f;
                    pb[4 + r] = __expf(num / dn);
                }
            }
        }
        union { __bf16 h[8]; bf16x8 v; } ap;
        #pragma unroll
        for (int jj = 0; jj < 8; ++jj) {
            den += pb[jj];
            ap.h[jj] = (__bf16)pb[jj];
        }

        const ushort* Vs = SMu + (br ? 24576 : 16384);
        #pragma unroll
        for (int t = 0; t < 16; ++t) {
            bf16x8 bV = *(const bf16x8*)(Vs + (t * 16 + l16) * 32 + vswo);
            acc[t] = __builtin_amdgcn_mfma_f32_16x16x32_bf16(ap.v, bV, acc[t], 0, 0, 0);
        }
    }

    den += __shfl_xor(den, 16, 64);
    den += __shfl_xor(den, 32, 64);
    float rdn[4];
    #pragma unroll
    for (int r = 0; r < 4; ++r)
        rdn[r] = 1.f / __shfl(den, quad * 4 + r, 64);

    __syncthreads();
    if (br) {
        #pragma unroll
        for (int t = 0; t < 16; ++t)
            #pragma unroll
            for (int r = 0; r < 4; ++r)
                combuf[(qsel * 16 + quad * 4 + r) * 256 + t * 16 + l16] = acc[t][r] * rdn[r];
    }
    __syncthreads();
    if (!br) {
        #pragma unroll
        for (int t = 0; t < 16; ++t)
            #pragma unroll
            for (int r = 0; r < 4; ++r) {
                int ql = qsel * 16 + quad * 4 + r;
                out[(size_t)(q0 + ql) * DM + t * 16 + l16] =
                    acc[t][r] * rdn[r] + combuf[ql * 256 + t * 16 + l16];
            }
    }
}

// ---------------- combine the MEM-quarters (per-branch normalize, sum) ----------
__global__ __launch_bounds__(256) void combine_halves(
    const float* __restrict__ part, const float* __restrict__ denp,
    float* __restrict__ out)
{
    const size_t stride = (size_t)NBQ * 64;         // floatx4 units per section
    const floatx4* p4 = (const floatx4*)part;
    floatx4* o4 = (floatx4*)out;
    #pragma unroll
    for (int u = 0; u < 2; ++u) {
        size_t i = (size_t)blockIdx.x * 512 + (size_t)u * 256 + threadIdx.x;
        int q = (int)(i >> 6);
        float dc = 0.f, ds = 0.f;
        #pragma unroll
        for (int h = 0; h < 4; ++h) {
            dc += denp[(size_t)h * NBQ + q];
            ds += denp[(size_t)(4 + h) * NBQ + q];
        }
        float rc = 1.f / dc, rs = 1.f / ds;
        floatx4 nc = {0.f, 0.f, 0.f, 0.f}, ns = {0.f, 0.f, 0.f, 0.f};
        #pragma unroll
        for (int h = 0; h < 4; ++h) {
            floatx4 c = __builtin_nontemporal_load(&p4[(size_t)h * stride + i]);
            floatx4 s = __builtin_nontemporal_load(&p4[(size_t)(4 + h) * stride + i]);
            nc += c;
            ns += s;
        }
        o4[i] = nc * rc + ns * rs;
    }
}

extern "C" void kernel_launch(void* const* d_in, const int* in_sizes, int n_in,
                              void* d_out, int out_size, void* d_ws, size_t ws_size,
                              hipStream_t stream)
{
    const float* x      = (const float*)d_in[0];
    const float* ch_mem = (const float*)d_in[1];
    const float* ch_wq  = (const float*)d_in[2];
    const float* ch_wk  = (const float*)d_in[3];
    const float* ch_wv  = (const float*)d_in[4];
    const float* sp_mem = (const float*)d_in[5];
    const float* sp_wq  = (const float*)d_in[6];
    const float* sp_wk  = (const float*)d_in[7];
    const float* sp_wv  = (const float*)d_in[8];
    float* out = (float*)d_out;

    ushort* Qb   = (ushort*)d_ws;                 // [12544][256]
    ushort* QFb  = Qb   + (size_t)NBQ * DM;
    ushort* Kb   = QFb  + (size_t)NBQ * DM;       // [2048][256]
    ushort* KFb  = Kb   + (size_t)MM * DM;
    ushort* Vtb  = KFb  + (size_t)MM * DM;        // [256][2048] transposed
    ushort* VFtb = Vtb  + (size_t)MM * DM;
    float*  km   = (float*)(VFtb + (size_t)MM * DM);
    float*  kv   = km + MM;
    float*  denp = kv + MM;                       // 8 sections x [12544]
    float*  part = denp + (size_t)8 * NBQ;        // 8 x [12544][256] f32

    const size_t base_b = (size_t)((char*)part - (char*)d_ws);
    const size_t need4  = base_b + (size_t)8 * NBQ * DM * sizeof(float);

    dim3 blk(256);
    gemm_proj_all<<<dim3(1040), blk, 0, stream>>>(
        x, ch_mem, ch_wq, ch_wk, ch_wv, sp_mem, sp_wq, sp_wk, sp_wv,
        Qb, QFb, Kb, KFb, Vtb, VFtb);
    row_stats_kf<<<dim3(MM / 4), blk, 0, stream>>>(KFb, km, kv);
    if (ws_size >= need4) {
        fused_attn_16w<<<dim3(392), dim3(1024), 0, stream>>>(
            Qb, QFb, Kb, KFb, Vtb, VFtb, km, kv, part, denp);
        combine_halves<<<dim3(NBQ * DM / 4 / 512), blk, 0, stream>>>(part, denp, out);
    } else {
        fused_attn_fb<<<dim3(NBQ / 32), blk, 0, stream>>>(
            Qb, QFb, Kb, KFb, Vtb, VFtb, km, kv, out);
    }
}

// Round 10
// 256.766 us; speedup vs baseline: 1.1417x; 1.1360x over previous
//
#include <hip/hip_runtime.h>

#define NBQ 12544
#define DM  256
#define MM  2048

typedef __attribute__((ext_vector_type(8)))  __bf16 bf16x8;
typedef __attribute__((ext_vector_type(4)))  float  floatx4;

__device__ __forceinline__ ushort f2bf(float x) {
    unsigned u = __float_as_uint(x);
    u += 0x7fffu + ((u >> 16) & 1u);   // RNE
    return (ushort)(u >> 16);
}
__device__ __forceinline__ float bf2f(ushort h) {
    return __uint_as_float(((unsigned)h) << 16);
}
__device__ __forceinline__ ushort4 cvt4(float4 f) {   // HW bf16 cvt (RNE, = f2bf)
    union { __bf16 h[4]; ushort4 u; } r;
    r.h[0] = (__bf16)f.x; r.h[1] = (__bf16)f.y;
    r.h[2] = (__bf16)f.z; r.h[3] = (__bf16)f.w;
    return r.u;
}

// async global->LDS, 16B per lane; dest = wave-uniform base + lane*16
__device__ __forceinline__ void glds16(const ushort* g, ushort* l) {
    __builtin_amdgcn_global_load_lds(
        (const __attribute__((address_space(1))) unsigned int*)g,
        (__attribute__((address_space(3))) unsigned int*)l, 16, 0, 0);
}

// ---------------- one-time f32 -> bf16 conversion (x, memories, 6 weights) -------
__global__ __launch_bounds__(256) void cvt_all_bf16(
    const float* __restrict__ x,   const float* __restrict__ ch_mem,
    const float* __restrict__ sp_mem,
    const float* __restrict__ cwq, const float* __restrict__ swq,
    const float* __restrict__ cwk, const float* __restrict__ cwv,
    const float* __restrict__ swk, const float* __restrict__ swv,
    ushort* __restrict__ xb, ushort* __restrict__ cmb,
    ushort* __restrict__ smb, ushort* __restrict__ wb)
{
    int bid = blockIdx.x;
    const float* src; ushort* dst; size_t off;
    if (bid < 392)      { src = x;      dst = xb;  off = (size_t)bid * 8192; }
    else if (bid < 456) { src = ch_mem; dst = cmb; off = (size_t)(bid - 392) * 8192; }
    else if (bid < 520) { src = sp_mem; dst = smb; off = (size_t)(bid - 456) * 8192; }
    else {
        int w = bid - 520, wi = w >> 3;
        if      (wi == 0) src = cwq;
        else if (wi == 1) src = swq;
        else if (wi == 2) src = cwk;
        else if (wi == 3) src = cwv;
        else if (wi == 4) src = swk;
        else              src = swv;
        dst = wb + (size_t)wi * 65536;
        off = (size_t)(w & 7) * 8192;
    }
    #pragma unroll
    for (int i = 0; i < 4; ++i) {
        size_t b = off + (size_t)i * 2048 + (size_t)threadIdx.x * 8;
        float4 a0 = *(const float4*)(src + b);
        float4 a1 = *(const float4*)(src + b + 4);
        *(ushort4*)(dst + b)     = cvt4(a0);
        *(ushort4*)(dst + b + 4) = cvt4(a1);
    }
}

// ---------------- bf16 projections: glds16 dbuf staging (fused-proven pipeline) ---
// Inputs pre-converted to bf16 (bit-identical RNE) -> staging is pure glds16, no
// f32 load + VALU cvt + ds_write round-trip (the r0-proj disease; proj was ~75us at
// a <10us roofline). Tiling/epilogue identical to the proven f32 proj. XOR chunk
// swizzle (slot = chunk ^ (row&7)) applied at the glds SOURCE and on frag reads.
#define PSTG(b, d0_)                                                          \
    { _Pragma("unroll") for (int p = 0; p < 2; ++p) {                         \
        int j = wv * 2 + p;                                                   \
        int R = j * 8 + (lane >> 3);                                          \
        int so = R * 256 + (d0_) + (((lane & 7) ^ (R & 7)) << 3);             \
        int doff = j * 512;                                                   \
        glds16(As_ + so, &SM[b][0][0][0] + doff);                             \
        glds16(W1_ + so, &SM[b][1][0][0] + doff);                             \
        glds16(W2_ + so, &SM[b][2][0][0] + doff);                             \
    } }

__global__ __launch_bounds__(256, 2) void gemm_proj_bf16(
    const ushort* __restrict__ xb,  const ushort* __restrict__ cmb,
    const ushort* __restrict__ smb, const ushort* __restrict__ wb,
    ushort* __restrict__ Qb,  ushort* __restrict__ QFb,
    ushort* __restrict__ Kb,  ushort* __restrict__ KFb,
    ushort* __restrict__ Vtb, ushort* __restrict__ VFtb)
{
    __shared__ ushort SM[2][3][64][64];   // 48 KB -> 2 blocks/CU

    int bid = blockIdx.x;
    const ushort* A; const ushort* W1; const ushort* W2;
    ushort* C1; ushort* C2; int nrows, trans2;
    if (bid < 784) {
        A = xb; W1 = wb; W2 = wb + 65536; C1 = Qb; C2 = QFb; nrows = NBQ; trans2 = 0;
    } else if (bid < 912) {
        A = cmb; W1 = wb + 2 * 65536; W2 = wb + 3 * 65536; C1 = Kb; C2 = Vtb;
        nrows = MM; trans2 = 1; bid -= 784;
    } else {
        A = smb; W1 = wb + 4 * 65536; W2 = wb + 5 * 65536; C1 = KFb; C2 = VFtb;
        nrows = MM; trans2 = 1; bid -= 912;
    }
    const int r0 = (bid >> 2) * 64;
    const int c0 = (bid & 3) * 64;

    const int tid  = threadIdx.x;
    const int wv   = tid >> 6;
    const int lane = tid & 63;
    const int quad = lane >> 4;
    const int l16  = lane & 15;
    const int rw = (wv & 1) * 32;
    const int cw = (wv >> 1) * 32;

    const ushort* As_ = A  + (size_t)r0 * 256;
    const ushort* W1_ = W1 + (size_t)c0 * 256;
    const ushort* W2_ = W2 + (size_t)c0 * 256;

    floatx4 acc1[2][2], acc2[2][2];
    #pragma unroll
    for (int i = 0; i < 2; ++i)
        #pragma unroll
        for (int j = 0; j < 2; ++j) {
            acc1[i][j] = (floatx4){0.f, 0.f, 0.f, 0.f};
            acc2[i][j] = (floatx4){0.f, 0.f, 0.f, 0.f};
        }

    PSTG(0, 0);
    __syncthreads();

    int buf = 0;
    const int kx = l16 & 7;
    for (int d0 = 0; d0 < 256; d0 += 64) {
        if (d0 + 64 < 256) PSTG(buf ^ 1, d0 + 64);
        #pragma unroll
        for (int kk = 0; kk < 64; kk += 32) {
            int off = (((kk >> 3) + quad) ^ kx) << 3;
            bf16x8 aA0 = *(const bf16x8*)&SM[buf][0][rw + l16][off];
            bf16x8 aA1 = *(const bf16x8*)&SM[buf][0][rw + 16 + l16][off];
            bf16x8 b10 = *(const bf16x8*)&SM[buf][1][cw + l16][off];
            bf16x8 b11 = *(const bf16x8*)&SM[buf][1][cw + 16 + l16][off];
            bf16x8 b20 = *(const bf16x8*)&SM[buf][2][cw + l16][off];
            bf16x8 b21 = *(const bf16x8*)&SM[buf][2][cw + 16 + l16][off];
            acc1[0][0] = __builtin_amdgcn_mfma_f32_16x16x32_bf16(aA0, b10, acc1[0][0], 0, 0, 0);
            acc1[0][1] = __builtin_amdgcn_mfma_f32_16x16x32_bf16(aA0, b11, acc1[0][1], 0, 0, 0);
            acc1[1][0] = __builtin_amdgcn_mfma_f32_16x16x32_bf16(aA1, b10, acc1[1][0], 0, 0, 0);
            acc1[1][1] = __builtin_amdgcn_mfma_f32_16x16x32_bf16(aA1, b11, acc1[1][1], 0, 0, 0);
            acc2[0][0] = __builtin_amdgcn_mfma_f32_16x16x32_bf16(aA0, b20, acc2[0][0], 0, 0, 0);
            acc2[0][1] = __builtin_amdgcn_mfma_f32_16x16x32_bf16(aA0, b21, acc2[0][1], 0, 0, 0);
            acc2[1][0] = __builtin_amdgcn_mfma_f32_16x16x32_bf16(aA1, b20, acc2[1][0], 0, 0, 0);
            acc2[1][1] = __builtin_amdgcn_mfma_f32_16x16x32_bf16(aA1, b21, acc2[1][1], 0, 0, 0);
        }
        __syncthreads();
        buf ^= 1;
    }

    #pragma unroll
    for (int ag = 0; ag < 2; ++ag)
        #pragma unroll
        for (int cg = 0; cg < 2; ++cg)
            #pragma unroll
            for (int i = 0; i < 4; ++i)
                C1[(size_t)(r0 + rw + ag * 16 + quad * 4 + i) * 256
                   + c0 + cw + cg * 16 + l16] = f2bf(acc1[ag][cg][i]);

    if (!trans2) {
        #pragma unroll
        for (int ag = 0; ag < 2; ++ag)
            #pragma unroll
            for (int cg = 0; cg < 2; ++cg)
                #pragma unroll
                for (int i = 0; i < 4; ++i)
                    C2[(size_t)(r0 + rw + ag * 16 + quad * 4 + i) * 256
                       + c0 + cw + cg * 16 + l16] = f2bf(acc2[ag][cg][i]);
    } else {
        __syncthreads();
        ushort (*W2s)[64] = SM[0][2];   // scratch (compute done); chunk-swizzled
        #pragma unroll
        for (int ag = 0; ag < 2; ++ag)
            #pragma unroll
            for (int cg = 0; cg < 2; ++cg)
                #pragma unroll
                for (int i = 0; i < 4; ++i) {
                    int col = rw + ag * 16 + quad * 4 + i;
                    int R   = cw + cg * 16 + l16;
                    W2s[R][(((col >> 3) ^ (R & 7)) << 3) + (col & 7)] =
                        f2bf(acc2[ag][cg][i]);
                }
        __syncthreads();
        const int col = tid >> 2;           // scratch row
        const int cj0 = (tid & 3) * 2;      // original chunk base
        #pragma unroll
        for (int j = 0; j < 2; ++j) {
            int oc = cj0 + j;
            *(uint4*)(C2 + (size_t)(c0 + col) * nrows + r0 + oc * 8) =
                *(const uint4*)&W2s[col][(oc ^ (col & 7)) << 3];
        }
    }
}

// ---------- fallback projections (f32 inputs staged + cvt; r3-proven) ----------
__global__ __launch_bounds__(256) void gemm_proj_all(
    const float* __restrict__ x,      const float* __restrict__ ch_mem,
    const float* __restrict__ ch_wq,  const float* __restrict__ ch_wk,
    const float* __restrict__ ch_wv,  const float* __restrict__ sp_mem,
    const float* __restrict__ sp_wq,  const float* __restrict__ sp_wk,
    const float* __restrict__ sp_wv,
    ushort* __restrict__ Qb,  ushort* __restrict__ QFb,
    ushort* __restrict__ Kb,  ushort* __restrict__ KFb,
    ushort* __restrict__ Vtb, ushort* __restrict__ VFtb)
{
    __shared__ ushort As[64][72];
    __shared__ ushort W1s[64][72];
    __shared__ ushort W2s[64][72];

    int bid = blockIdx.x;
    const float* A; const float* W1; const float* W2;
    ushort* C1; ushort* C2; int nrows, trans2;
    if (bid < 784) {
        A = x; W1 = ch_wq; W2 = sp_wq; C1 = Qb; C2 = QFb; nrows = NBQ; trans2 = 0;
    } else if (bid < 912) {
        A = ch_mem; W1 = ch_wk; W2 = ch_wv; C1 = Kb; C2 = Vtb;
        nrows = MM; trans2 = 1; bid -= 784;
    } else {
        A = sp_mem; W1 = sp_wk; W2 = sp_wv; C1 = KFb; C2 = VFtb;
        nrows = MM; trans2 = 1; bid -= 912;
    }
    const int r0 = (bid >> 2) * 64;
    const int c0 = (bid & 3) * 64;

    const int tid  = threadIdx.x;
    const int wv   = tid >> 6;
    const int lane = tid & 63;
    const int quad = lane >> 4;
    const int l16  = lane & 15;
    const int rw = (wv & 1) * 32;
    const int cw = (wv >> 1) * 32;

    floatx4 acc1[2][2], acc2[2][2];
    #pragma unroll
    for (int i = 0; i < 2; ++i)
        #pragma unroll
        for (int j = 0; j < 2; ++j) {
            acc1[i][j] = (floatx4){0.f, 0.f, 0.f, 0.f};
            acc2[i][j] = (floatx4){0.f, 0.f, 0.f, 0.f};
        }

    float4 a4[4], w14[4], w24[4];
    #pragma unroll
    for (int it = 0; it < 4; ++it) {
        int idx = tid + it * 256;
        int r = idx >> 4, c4 = (idx & 15) * 4;
        a4[it]  = *(const float4*)(A  + (size_t)(r0 + r) * 256 + c4);
        w14[it] = *(const float4*)(W1 + (size_t)(c0 + r) * 256 + c4);
        w24[it] = *(const float4*)(W2 + (size_t)(c0 + r) * 256 + c4);
    }

    for (int d0 = 0; d0 < 256; d0 += 64) {
        __syncthreads();
        #pragma unroll
        for (int it = 0; it < 4; ++it) {
            int idx = tid + it * 256;
            int r = idx >> 4, c4 = (idx & 15) * 4;
            *(ushort4*)&As[r][c4]  = cvt4(a4[it]);
            *(ushort4*)&W1s[r][c4] = cvt4(w14[it]);
            *(ushort4*)&W2s[r][c4] = cvt4(w24[it]);
        }
        if (d0 + 64 < 256) {
            #pragma unroll
            for (int it = 0; it < 4; ++it) {
                int idx = tid + it * 256;
                int r = idx >> 4, c4 = (idx & 15) * 4;
                a4[it]  = *(const float4*)(A  + (size_t)(r0 + r) * 256 + d0 + 64 + c4);
                w14[it] = *(const float4*)(W1 + (size_t)(c0 + r) * 256 + d0 + 64 + c4);
                w24[it] = *(const float4*)(W2 + (size_t)(c0 + r) * 256 + d0 + 64 + c4);
            }
        }
        __syncthreads();
        #pragma unroll
        for (int kk = 0; kk < 64; kk += 32) {
            bf16x8 aA0 = *(const bf16x8*)&As[rw + l16][kk + quad * 8];
            bf16x8 aA1 = *(const bf16x8*)&As[rw + 16 + l16][kk + quad * 8];
            bf16x8 b10 = *(const bf16x8*)&W1s[cw + l16][kk + quad * 8];
            bf16x8 b11 = *(const bf16x8*)&W1s[cw + 16 + l16][kk + quad * 8];
            bf16x8 b20 = *(const bf16x8*)&W2s[cw + l16][kk + quad * 8];
            bf16x8 b21 = *(const bf16x8*)&W2s[cw + 16 + l16][kk + quad * 8];
            acc1[0][0] = __builtin_amdgcn_mfma_f32_16x16x32_bf16(aA0, b10, acc1[0][0], 0, 0, 0);
            acc1[0][1] = __builtin_amdgcn_mfma_f32_16x16x32_bf16(aA0, b11, acc1[0][1], 0, 0, 0);
            acc1[1][0] = __builtin_amdgcn_mfma_f32_16x16x32_bf16(aA1, b10, acc1[1][0], 0, 0, 0);
            acc1[1][1] = __builtin_amdgcn_mfma_f32_16x16x32_bf16(aA1, b11, acc1[1][1], 0, 0, 0);
            acc2[0][0] = __builtin_amdgcn_mfma_f32_16x16x32_bf16(aA0, b20, acc2[0][0], 0, 0, 0);
            acc2[0][1] = __builtin_amdgcn_mfma_f32_16x16x32_bf16(aA0, b21, acc2[0][1], 0, 0, 0);
            acc2[1][0] = __builtin_amdgcn_mfma_f32_16x16x32_bf16(aA1, b20, acc2[1][0], 0, 0, 0);
            acc2[1][1] = __builtin_amdgcn_mfma_f32_16x16x32_bf16(aA1, b21, acc2[1][1], 0, 0, 0);
        }
    }

    #pragma unroll
    for (int ag = 0; ag < 2; ++ag)
        #pragma unroll
        for (int cg = 0; cg < 2; ++cg)
            #pragma unroll
            for (int i = 0; i < 4; ++i)
                C1[(size_t)(r0 + rw + ag * 16 + quad * 4 + i) * 256
                   + c0 + cw + cg * 16 + l16] = f2bf(acc1[ag][cg][i]);

    if (!trans2) {
        #pragma unroll
        for (int ag = 0; ag < 2; ++ag)
            #pragma unroll
            for (int cg = 0; cg < 2; ++cg)
                #pragma unroll
                for (int i = 0; i < 4; ++i)
                    C2[(size_t)(r0 + rw + ag * 16 + quad * 4 + i) * 256
                       + c0 + cw + cg * 16 + l16] = f2bf(acc2[ag][cg][i]);
    } else {
        __syncthreads();
        #pragma unroll
        for (int ag = 0; ag < 2; ++ag)
            #pragma unroll
            for (int cg = 0; cg < 2; ++cg)
                #pragma unroll
                for (int i = 0; i < 4; ++i)
                    W2s[cw + cg * 16 + l16][rw + ag * 16 + quad * 4 + i] = f2bf(acc2[ag][cg][i]);
        __syncthreads();
        const int col = tid >> 2;
        const int seg = (tid & 3) * 16;
        #pragma unroll
        for (int j = 0; j < 2; ++j)
            *(uint4*)(C2 + (size_t)(c0 + col) * nrows + r0 + seg + j * 8) =
                *(const uint4*)&W2s[col][seg + j * 8];
    }
}

// -------- KF row stats (kv stores variance + 0.03 pre-folded) ----------------
__global__ __launch_bounds__(256) void row_stats_kf(
    const ushort* __restrict__ KFb, float* __restrict__ km, float* __restrict__ kv)
{
    const int row  = blockIdx.x * 4 + (threadIdx.x >> 6);
    const int lane = threadIdx.x & 63;
    ushort4 u = *(const ushort4*)(KFb + (size_t)row * 256 + lane * 4);
    float a = bf2f(u.x), b = bf2f(u.y), c = bf2f(u.z), d = bf2f(u.w);
    float s  = a + b + c + d;
    float ss = a * a + b * b + c * c + d * d;
    #pragma unroll
    for (int off = 32; off > 0; off >>= 1) {
        s  += __shfl_down(s, off);
        ss += __shfl_down(ss, off);
    }
    if (lane == 0) {
        float m = s * (1.f / 256.f);
        km[row] = m;
        kv[row] = (ss - 256.f * m * m) * (1.f / 255.f) + 0.03f;
    }
}

// ---------------- fused attention (r3-proven 157us kernel, verbatim) --------------
// 32q/wave, 4-wave blocks, BQ=128, NH=4 MEM-split, dbuf glds staging with the
// single-syncthreads pipeline. r6-r9 established Qw=16 variants all regress to
// ~185-190us (LDS-read demand doubles per query); this corner is the structure's
// proven optimum.
#define STAGE_TILE(b, ti)                                                     \
    {                                                                         \
        const ushort* kp_ = kp0 + (size_t)(ti) * 32 * DM;                     \
        const ushort* vp_ = vp0 + (ti) * 32;                                  \
        ushort* dst_ = SMu + (b) * 16384;                                     \
        _Pragma("unroll")                                                     \
        for (int p = 0; p < 4; ++p) {                                         \
            int db = (wv * 4 + p) * 512;                                      \
            glds16(kp_ + offK[p], dst_ + db);                                 \
            glds16(vp_ + offV[p], dst_ + 8192 + db);                          \
        }                                                                     \
    }

template<int NHALF>
__global__ __launch_bounds__(256, 2) void fused_attn_1br(
    const ushort* __restrict__ Qb,  const ushort* __restrict__ QFb,
    const ushort* __restrict__ Kb,  const ushort* __restrict__ KFb,
    const ushort* __restrict__ Vtb, const ushort* __restrict__ VFtb,
    const float* __restrict__ km_, const float* __restrict__ kv_,
    float* __restrict__ part, float* __restrict__ denp)
{
    __shared__ ushort SMu[32768];   // 64KB: buf{0,1} x {K 16KB, Vt 16KB}

    const int tid  = threadIdx.x;
    const int wv   = tid >> 6;
    const int lane = tid & 63;
    const int quad = lane >> 4;
    const int l16  = lane & 15;

    const int NQC = NBQ / 128;             // 98
    const int per_br = NQC * NHALF;
    int bid = blockIdx.x;
    const int br  = (bid < per_br) ? 1 : 0;     // sp blocks first (heavier)
    int rem = br ? bid : bid - per_br;
    const int half = rem / NQC;
    const int qc   = rem - half * NQC;
    const int q0   = qc * 128;
    const int kbase = half * (MM / NHALF);
    const int NT   = (MM / NHALF) / 32;

    const ushort* qsrc = br ? QFb : Qb;
    const ushort* Ksel = br ? KFb : Kb;
    const ushort* Vsel = br ? VFtb : Vtb;

    bf16x8 aQ0[8], aQ1[8];
    {
        const ushort* qp = qsrc + (size_t)(q0 + wv * 32 + l16) * DM + quad * 8;
        #pragma unroll
        for (int s = 0; s < 8; ++s) {
            aQ0[s] = *(const bf16x8*)(qp + s * 32);
            aQ1[s] = *(const bf16x8*)(qp + 16 * DM + s * 32);
        }
    }

    float qmv0 = 0.f, qvv0 = 0.f, qmv1 = 0.f, qvv1 = 0.f, qm20 = 0.f, qm21 = 0.f;
    if (br) {
        float s0 = 0.f, ss0 = 0.f, s1 = 0.f, ss1 = 0.f;
        #pragma unroll
        for (int s = 0; s < 8; ++s)
            #pragma unroll
            for (int j = 0; j < 8; ++j) {
                float v0 = (float)aQ0[s][j], v1 = (float)aQ1[s][j];
                s0 += v0; ss0 += v0 * v0; s1 += v1; ss1 += v1 * v1;
            }
        s0  += __shfl_xor(s0, 16, 64);  s0  += __shfl_xor(s0, 32, 64);
        ss0 += __shfl_xor(ss0, 16, 64); ss0 += __shfl_xor(ss0, 32, 64);
        s1  += __shfl_xor(s1, 16, 64);  s1  += __shfl_xor(s1, 32, 64);
        ss1 += __shfl_xor(ss1, 16, 64); ss1 += __shfl_xor(ss1, 32, 64);
        qmv0 = s0 * (1.f / 256.f);
        qvv0 = (ss0 - 256.f * qmv0 * qmv0) * (1.f / 255.f);
        qmv1 = s1 * (1.f / 256.f);
        qvv1 = (ss1 - 256.f * qmv1 * qmv1) * (1.f / 255.f);
        qm20 = qmv0 * qmv0 + 0.01f;
        qm21 = qmv1 * qmv1 + 0.01f;
    }

    int offK[4], offV[4];
    #pragma unroll
    for (int p = 0; p < 4; ++p) {
        int j  = wv * 4 + p;
        int Rk = 2 * j + (lane >> 5);
        int rk = (Rk & 3) + ((Rk >> 4) & 1) * 4 + ((Rk >> 2) & 3) * 8;   // prinv
        int ck = (lane & 31) ^ (Rk & 7);
        offK[p] = rk * DM + ck * 8;
        int Rv = 16 * j + (lane >> 2);
        int cv = (lane & 3) ^ (Rv & 3);
        offV[p] = Rv * MM + cv * 8;
    }

    const ushort* kp0 = Ksel + (size_t)kbase * DM;
    const ushort* vp0 = Vsel + kbase;

    floatx4 acc0[16], acc1[16];
    #pragma unroll
    for (int t = 0; t < 16; ++t) {
        acc0[t] = (floatx4){0.f, 0.f, 0.f, 0.f};
        acc1[t] = (floatx4){0.f, 0.f, 0.f, 0.f};
    }
    float den0 = 0.f, den1 = 0.f;
    const int ksw  = l16 & 7;
    const int vswo = (quad ^ (l16 & 3)) * 8;

    STAGE_TILE(0, 0);
    __syncthreads();

    int buf = 0;
    for (int ti = 0; ti < NT; ++ti) {
        if (ti + 1 < NT) STAGE_TILE(buf ^ 1, ti + 1);   // issue-early, wait-late

        const ushort* Ks = SMu + buf * 16384;
        const ushort* Vs = Ks + 8192;

        floatx4 S00 = (floatx4){0.f, 0.f, 0.f, 0.f};
        floatx4 S10 = (floatx4){0.f, 0.f, 0.f, 0.f};
        floatx4 S01 = (floatx4){0.f, 0.f, 0.f, 0.f};
        floatx4 S11 = (floatx4){0.f, 0.f, 0.f, 0.f};
        #pragma unroll
        for (int s = 0; s < 8; ++s) {
            int off = ((s * 4 + quad) ^ ksw) * 8;
            bf16x8 aK0 = *(const bf16x8*)(Ks + l16 * DM + off);
            bf16x8 aK1 = *(const bf16x8*)(Ks + 4096 + l16 * DM + off);
            S00 = __builtin_amdgcn_mfma_f32_16x16x32_bf16(aK0, aQ0[s], S00, 0, 0, 0);
            S10 = __builtin_amdgcn_mfma_f32_16x16x32_bf16(aK1, aQ0[s], S10, 0, 0, 0);
            S01 = __builtin_amdgcn_mfma_f32_16x16x32_bf16(aK0, aQ1[s], S01, 0, 0, 0);
            S11 = __builtin_amdgcn_mfma_f32_16x16x32_bf16(aK1, aQ1[s], S11, 0, 0, 0);
        }

        const int kk = kbase + ti * 32;
        float p0[8], p1[8];
        if (!br) {
            #pragma unroll
            for (int r = 0; r < 4; ++r) {
                p0[r]     = __expf(S00[r] * 0.0625f);
                p0[4 + r] = __expf(S10[r] * 0.0625f);
                p1[r]     = __expf(S01[r] * 0.0625f);
                p1[4 + r] = __expf(S11[r] * 0.0625f);
            }
        } else {
            floatx4 km0 = *(const floatx4*)(km_ + kk + 8 * quad);
            floatx4 km1 = *(const floatx4*)(km_ + kk + 8 * quad + 4);
            floatx4 kv0 = *(const floatx4*)(kv_ + kk + 8 * quad);
            floatx4 kv1 = *(const floatx4*)(kv_ + kk + 8 * quad + 4);
            #pragma unroll
            for (int r = 0; r < 4; ++r) {
                {
                    float kmr = km0[r];
                    float mp  = qmv0 * kmr;
                    float cov = (S00[r] - 256.f * mp) * (1.f / 255.f);
                    float num = (2.f * mp + 0.01f) * (2.f * cov + 0.03f);
                    float dn  = (qm20 + kmr * kmr) * (qvv0 + kv0[r]) + 1e-8f;
                    p0[r] = __expf(num / dn);
                }
                {
                    float kmr = km1[r];
                    float mp  = qmv0 * kmr;
                    float cov = (S10[r] - 256.f * mp) * (1.f / 255.f);
                    float num = (2.f * mp + 0.01f) * (2.f * cov + 0.03f);
                    float dn  = (qm20 + kmr * kmr) * (qvv0 + kv1[r]) + 1e-8f;
                    p0[4 + r] = __expf(num / dn);
                }
                {
                    float kmr = km0[r];
                    float mp  = qmv1 * kmr;
                    float cov = (S01[r] - 256.f * mp) * (1.f / 255.f);
                    float num = (2.f * mp + 0.01f) * (2.f * cov + 0.03f);
                    float dn  = (qm21 + kmr * kmr) * (qvv1 + kv0[r]) + 1e-8f;
                    p1[r] = __expf(num / dn);
                }
                {
                    float kmr = km1[r];
                    float mp  = qmv1 * kmr;
                    float cov = (S11[r] - 256.f * mp) * (1.f / 255.f);
                    float num = (2.f * mp + 0.01f) * (2.f * cov + 0.03f);
                    float dn  = (qm21 + kmr * kmr) * (qvv1 + kv1[r]) + 1e-8f;
                    p1[4 + r] = __expf(num / dn);
                }
            }
        }
        union { __bf16 h[8]; bf16x8 v; } ap0, ap1;
        #pragma unroll
        for (int j = 0; j < 8; ++j) {
            den0 += p0[j]; ap0.h[j] = (__bf16)p0[j];
            den1 += p1[j]; ap1.h[j] = (__bf16)p1[j];
        }

        #pragma unroll
        for (int t = 0; t < 16; ++t) {
            bf16x8 bV = *(const bf16x8*)(Vs + (t * 16 + l16) * 32 + vswo);
            acc0[t] = __builtin_amdgcn_mfma_f32_16x16x32_bf16(ap0.v, bV, acc0[t], 0, 0, 0);
            acc1[t] = __builtin_amdgcn_mfma_f32_16x16x32_bf16(ap1.v, bV, acc1[t], 0, 0, 0);
        }

        __syncthreads();     // drains vmcnt(0): prefetch had full compute phase to land
        buf ^= 1;
    }

    den0 += __shfl_xor(den0, 16, 64); den0 += __shfl_xor(den0, 32, 64);
    den1 += __shfl_xor(den1, 16, 64); den1 += __shfl_xor(den1, 32, 64);

    const int sec = br * NHALF + half;
    float* Np = part + (size_t)sec * ((size_t)NBQ * DM);
    #pragma unroll
    for (int t = 0; t < 16; ++t)
        #pragma unroll
        for (int r = 0; r < 4; ++r) {
            int row = q0 + wv * 32 + quad * 4 + r;
            Np[(size_t)row * DM + t * 16 + l16]        = acc0[t][r];
            Np[(size_t)(row + 16) * DM + t * 16 + l16] = acc1[t][r];
        }
    if (lane < 16) {
        denp[(size_t)sec * NBQ + q0 + wv * 32 + lane]      = den0;
        denp[(size_t)sec * NBQ + q0 + wv * 32 + 16 + lane] = den1;
    }
}

// ---------------- fallback fused (direct out; small ws) ---------------------------
__global__ __launch_bounds__(256, 2) void fused_attn_fb(
    const ushort* __restrict__ Qb,  const ushort* __restrict__ QFb,
    const ushort* __restrict__ Kb,  const ushort* __restrict__ KFb,
    const ushort* __restrict__ Vtb, const ushort* __restrict__ VFtb,
    const float* __restrict__ km_, const float* __restrict__ kv_,
    float* __restrict__ out)
{
    __shared__ ushort SMu[32768];
    float* combuf = (float*)SMu;

    const int tid  = threadIdx.x;
    const int wv   = tid >> 6;
    const int lane = tid & 63;
    const int quad = lane >> 4;
    const int l16  = lane & 15;
    const int qsel = wv & 1;
    const int br   = wv >> 1;
    const int q0   = blockIdx.x * 32;

    const ushort* qsrc = br ? QFb : Qb;
    bf16x8 aQ[8];
    {
        const ushort* qp = qsrc + (size_t)(q0 + qsel * 16 + l16) * DM + quad * 8;
        #pragma unroll
        for (int s = 0; s < 8; ++s) aQ[s] = *(const bf16x8*)(qp + s * 32);
    }

    float qmv = 0.f, qvv = 0.f, qm2 = 0.f;
    if (br) {
        float sum = 0.f, ss = 0.f;
        #pragma unroll
        for (int s = 0; s < 8; ++s)
            #pragma unroll
            for (int jj = 0; jj < 8; ++jj) {
                float v = (float)aQ[s][jj];
                sum += v; ss += v * v;
            }
        sum += __shfl_xor(sum, 16, 64); sum += __shfl_xor(sum, 32, 64);
        ss  += __shfl_xor(ss, 16, 64);  ss  += __shfl_xor(ss, 32, 64);
        qmv = sum * (1.f / 256.f);
        qvv = (ss - 256.f * qmv * qmv) * (1.f / 255.f);
        qm2 = qmv * qmv + 0.01f;
    }

    int offK[4], offV[4];
    #pragma unroll
    for (int p = 0; p < 4; ++p) {
        int jw = wv * 4 + p;
        int Rk = 2 * jw + (lane >> 5);
        int rk = (Rk & 3) + ((Rk >> 4) & 1) * 4 + ((Rk >> 2) & 3) * 8;
        int ck = (lane & 31) ^ (Rk & 7);
        offK[p] = rk * DM + ck * 8;
        int Rv = 16 * jw + (lane >> 2);
        int cv = (lane & 3) ^ (Rv & 3);
        offV[p] = Rv * MM + cv * 8;
    }

    const ushort* kp  = Kb;
    const ushort* kfp = KFb;
    const ushort* vp  = Vtb;
    const ushort* vfp = VFtb;

    floatx4 acc[16];
    #pragma unroll
    for (int t = 0; t < 16; ++t) acc[t] = (floatx4){0.f, 0.f, 0.f, 0.f};
    float den = 0.f;

    const int ksw  = l16 & 7;
    const int vswo = (quad ^ (l16 & 3)) * 8;

    for (int kt = 0; kt < MM; kt += 32) {
        __syncthreads();
        #pragma unroll
        for (int p = 0; p < 4; ++p) {
            int db = (wv * 4 + p) * 512;
            glds16(kp  + offK[p], SMu + db);
            glds16(kfp + offK[p], SMu + 8192 + db);
            glds16(vp  + offV[p], SMu + 16384 + db);
            glds16(vfp + offV[p], SMu + 24576 + db);
        }
        kp += 32 * DM; kfp += 32 * DM; vp += 32; vfp += 32;
        __syncthreads();

        const ushort* Ks = SMu + (br ? 8192 : 0);
        floatx4 S0 = (floatx4){0.f, 0.f, 0.f, 0.f};
        floatx4 S1 = (floatx4){0.f, 0.f, 0.f, 0.f};
        #pragma unroll
        for (int s = 0; s < 8; ++s) {
            int off = ((s * 4 + quad) ^ ksw) * 8;
            bf16x8 aK0 = *(const bf16x8*)(Ks + l16 * DM + off);
            bf16x8 aK1 = *(const bf16x8*)(Ks + 4096 + l16 * DM + off);
            S0 = __builtin_amdgcn_mfma_f32_16x16x32_bf16(aK0, aQ[s], S0, 0, 0, 0);
            S1 = __builtin_amdgcn_mfma_f32_16x16x32_bf16(aK1, aQ[s], S1, 0, 0, 0);
        }

        float pb[8];
        if (!br) {
            #pragma unroll
            for (int r = 0; r < 4; ++r) {
                pb[r]     = __expf(S0[r] * 0.0625f);
                pb[4 + r] = __expf(S1[r] * 0.0625f);
            }
        } else {
            floatx4 km0 = *(const floatx4*)(km_ + kt + 8 * quad);
            floatx4 km1 = *(const floatx4*)(km_ + kt + 8 * quad + 4);
            floatx4 kv0 = *(const floatx4*)(kv_ + kt + 8 * quad);
            floatx4 kv1 = *(const floatx4*)(kv_ + kt + 8 * quad + 4);
            #pragma unroll
            for (int r = 0; r < 4; ++r) {
                {
                    float kmr = km0[r];
                    float mp  = qmv * kmr;
                    float cov = (S0[r] - 256.f * mp) * (1.f / 255.f);
                    float num = (2.f * mp + 0.01f) * (2.f * cov + 0.03f);
                    float dn  = (qm2 + kmr * kmr) * (qvv + kv0[r]) + 1e-8f;
                    pb[r] = __expf(num / dn);
                }
                {
                    float kmr = km1[r];
                    float mp  = qmv * kmr;
                    float cov = (S1[r] - 256.f * mp) * (1.f / 255.f);
                    float num = (2.f * mp + 0.01f) * (2.f * cov + 0.03f);
                    float dn  = (qm2 + kmr * kmr) * (qvv + kv1[r]) + 1e-8f;
                    pb[4 + r] = __expf(num / dn);
                }
            }
        }
        union { __bf16 h[8]; bf16x8 v; } ap;
        #pragma unroll
        for (int jj = 0; jj < 8; ++jj) {
            den += pb[jj];
            ap.h[jj] = (__bf16)pb[jj];
        }

        const ushort* Vs = SMu + (br ? 24576 : 16384);
        #pragma unroll
        for (int t = 0; t < 16; ++t) {
            bf16x8 bV = *(const bf16x8*)(Vs + (t * 16 + l16) * 32 + vswo);
            acc[t] = __builtin_amdgcn_mfma_f32_16x16x32_bf16(ap.v, bV, acc[t], 0, 0, 0);
        }
    }

    den += __shfl_xor(den, 16, 64);
    den += __shfl_xor(den, 32, 64);
    float rdn[4];
    #pragma unroll
    for (int r = 0; r < 4; ++r)
        rdn[r] = 1.f / __shfl(den, quad * 4 + r, 64);

    __syncthreads();
    if (br) {
        #pragma unroll
        for (int t = 0; t < 16; ++t)
            #pragma unroll
            for (int r = 0; r < 4; ++r)
                combuf[(qsel * 16 + quad * 4 + r) * 256 + t * 16 + l16] = acc[t][r] * rdn[r];
    }
    __syncthreads();
    if (!br) {
        #pragma unroll
        for (int t = 0; t < 16; ++t)
            #pragma unroll
            for (int r = 0; r < 4; ++r) {
                int ql = qsel * 16 + quad * 4 + r;
                out[(size_t)(q0 + ql) * DM + t * 16 + l16] =
                    acc[t][r] * rdn[r] + combuf[ql * 256 + t * 16 + l16];
            }
    }
}

// ---------------- combine the MEM-quarters (per-branch normalize, sum) ----------
__global__ __launch_bounds__(256) void combine_halves(
    const float* __restrict__ part, const float* __restrict__ denp,
    float* __restrict__ out)
{
    const size_t stride = (size_t)NBQ * 64;         // floatx4 units per section
    const floatx4* p4 = (const floatx4*)part;
    floatx4* o4 = (floatx4*)out;
    #pragma unroll
    for (int u = 0; u < 2; ++u) {
        size_t i = (size_t)blockIdx.x * 512 + (size_t)u * 256 + threadIdx.x;
        int q = (int)(i >> 6);
        float dc = 0.f, ds = 0.f;
        #pragma unroll
        for (int h = 0; h < 4; ++h) {
            dc += denp[(size_t)h * NBQ + q];
            ds += denp[(size_t)(4 + h) * NBQ + q];
        }
        float rc = 1.f / dc, rs = 1.f / ds;
        floatx4 nc = {0.f, 0.f, 0.f, 0.f}, ns = {0.f, 0.f, 0.f, 0.f};
        #pragma unroll
        for (int h = 0; h < 4; ++h) {
            floatx4 c = __builtin_nontemporal_load(&p4[(size_t)h * stride + i]);
            floatx4 s = __builtin_nontemporal_load(&p4[(size_t)(4 + h) * stride + i]);
            nc += c;
            ns += s;
        }
        o4[i] = nc * rc + ns * rs;
    }
}

extern "C" void kernel_launch(void* const* d_in, const int* in_sizes, int n_in,
                              void* d_out, int out_size, void* d_ws, size_t ws_size,
                              hipStream_t stream)
{
    const float* x      = (const float*)d_in[0];
    const float* ch_mem = (const float*)d_in[1];
    const float* ch_wq  = (const float*)d_in[2];
    const float* ch_wk  = (const float*)d_in[3];
    const float* ch_wv  = (const float*)d_in[4];
    const float* sp_mem = (const float*)d_in[5];
    const float* sp_wq  = (const float*)d_in[6];
    const float* sp_wk  = (const float*)d_in[7];
    const float* sp_wv  = (const float*)d_in[8];
    float* out = (float*)d_out;

    ushort* Qb   = (ushort*)d_ws;                 // [12544][256]
    ushort* QFb  = Qb   + (size_t)NBQ * DM;
    ushort* Kb   = QFb  + (size_t)NBQ * DM;       // [2048][256]
    ushort* KFb  = Kb   + (size_t)MM * DM;
    ushort* Vtb  = KFb  + (size_t)MM * DM;        // [256][2048] transposed
    ushort* VFtb = Vtb  + (size_t)MM * DM;
    float*  km   = (float*)(VFtb + (size_t)MM * DM);
    float*  kv   = km + MM;
    float*  denp = kv + MM;                       // 8 sections x [12544]
    float*  part = denp + (size_t)8 * NBQ;        // 8 x [12544][256] f32
    ushort* xb   = (ushort*)(part + (size_t)8 * NBQ * DM);   // bf16 inputs
    ushort* cmb  = xb  + (size_t)NBQ * DM;
    ushort* smb  = cmb + (size_t)MM * DM;
    ushort* wb   = smb + (size_t)MM * DM;         // 6 x [256][256] bf16 weights

    const size_t need4 = (size_t)((char*)xb - (char*)d_ws);
    const size_t need5 = (size_t)((char*)(wb + (size_t)6 * DM * DM) - (char*)d_ws);

    dim3 blk(256);
    if (ws_size >= need5) {
        cvt_all_bf16<<<dim3(568), blk, 0, stream>>>(
            x, ch_mem, sp_mem, ch_wq, sp_wq, ch_wk, ch_wv, sp_wk, sp_wv,
            xb, cmb, smb, wb);
        gemm_proj_bf16<<<dim3(1040), blk, 0, stream>>>(
            xb, cmb, smb, wb, Qb, QFb, Kb, KFb, Vtb, VFtb);
    } else {
        gemm_proj_all<<<dim3(1040), blk, 0, stream>>>(
            x, ch_mem, ch_wq, ch_wk, ch_wv, sp_mem, sp_wq, sp_wk, sp_wv,
            Qb, QFb, Kb, KFb, Vtb, VFtb);
    }
    row_stats_kf<<<dim3(MM / 4), blk, 0, stream>>>(KFb, km, kv);
    if (ws_size >= need4) {
        fused_attn_1br<4><<<dim3(784), blk, 0, stream>>>(
            Qb, QFb, Kb, KFb, Vtb, VFtb, km, kv, part, denp);
        combine_halves<<<dim3(NBQ * DM / 4 / 512), blk, 0, stream>>>(part, denp, out);
    } else {
        fused_attn_fb<<<dim3(NBQ / 32), blk, 0, stream>>>(
            Qb, QFb, Kb, KFb, Vtb, VFtb, km, kv, out);
    }
}